// Round 1
// baseline (9446.856 us; speedup 1.0000x reference)
//
#include <hip/hip_runtime.h>
#include <math.h>

#define N 2048
#define D 256
#define NM (N*N)            // 4194304 elements per matrix
#define REG 0.1f
#define EPSF 1e-10f
#define INV_N (1.0f/2048.0f)
#define P0CONST (1.0f/(2048.0f*2048.0f))
#define PROX 5
#define SINK 100

__device__ __forceinline__ float waveReduceSum(float v){
#pragma unroll
    for(int o=32;o;o>>=1) v += __shfl_xor(v,o,64);
    return v;
}
__device__ __forceinline__ float waveReduceMax(float v){
#pragma unroll
    for(int o=32;o;o>>=1) v = fmaxf(v, __shfl_xor(v,o,64));
    return v;
}

// ---------------- row squared-norms of x and y ----------------
__global__ __launch_bounds__(256) void norms_k(const float* __restrict__ x,
                                               const float* __restrict__ y,
                                               float* __restrict__ nx,
                                               float* __restrict__ ny){
    const float* src = blockIdx.y ? y : x;
    float* dst       = blockIdx.y ? ny : nx;
    int w = threadIdx.x >> 6, lane = threadIdx.x & 63;
    int row = blockIdx.x*4 + w;
    const float4* r4 = (const float4*)(src + (size_t)row*D);
    float4 f = r4[lane];                       // 64 lanes * float4 = 256 floats
    float s = f.x*f.x + f.y*f.y + f.z*f.z + f.w*f.w;
    s = waveReduceSum(s);
    if(lane==0) dst[row] = s;
}

// ---------------- C = |a_i|^2 + |b_j|^2 - 2 a_i.b_j  (3 matrices via blockIdx.y) --------
__global__ __launch_bounds__(256) void sqdist_k(const float* __restrict__ x,
                                                const float* __restrict__ y,
                                                const float* __restrict__ nx,
                                                const float* __restrict__ ny,
                                                float* __restrict__ Cb){
    int mat = blockIdx.y;
    const float* A  = (mat<2)  ? x  : y;
    const float* B  = (mat==0) ? x  : y;
    const float* na = (mat<2)  ? nx : ny;
    const float* nb = (mat==0) ? nx : ny;
    float* Cm = Cb + (size_t)mat*NM;
    int bm = blockIdx.x >> 5, bn = blockIdx.x & 31;
    __shared__ float As[32][68];
    __shared__ float Bs[32][68];
    int tid = threadIdx.x;
    int tr = tid >> 4, tc = tid & 15;
    float acc[4][4] = {};
    for(int kb=0; kb<8; ++kb){
#pragma unroll
        for(int i=0;i<2;++i){
            int id = tid + 256*i;
            int r = id >> 3, c4 = id & 7;
            float4 a = *(const float4*)(A + (size_t)(bm*64 + r)*D + kb*32 + c4*4);
            As[c4*4+0][r]=a.x; As[c4*4+1][r]=a.y; As[c4*4+2][r]=a.z; As[c4*4+3][r]=a.w;
            float4 b = *(const float4*)(B + (size_t)(bn*64 + r)*D + kb*32 + c4*4);
            Bs[c4*4+0][r]=b.x; Bs[c4*4+1][r]=b.y; Bs[c4*4+2][r]=b.z; Bs[c4*4+3][r]=b.w;
        }
        __syncthreads();
#pragma unroll
        for(int d=0; d<32; ++d){
            float4 a = *(const float4*)&As[d][4*tr];
            float4 b = *(const float4*)&Bs[d][4*tc];
            acc[0][0] += a.x*b.x; acc[0][1] += a.x*b.y; acc[0][2] += a.x*b.z; acc[0][3] += a.x*b.w;
            acc[1][0] += a.y*b.x; acc[1][1] += a.y*b.y; acc[1][2] += a.y*b.z; acc[1][3] += a.y*b.w;
            acc[2][0] += a.z*b.x; acc[2][1] += a.z*b.y; acc[2][2] += a.z*b.z; acc[2][3] += a.z*b.w;
            acc[3][0] += a.w*b.x; acc[3][1] += a.w*b.y; acc[3][2] += a.w*b.z; acc[3][3] += a.w*b.w;
        }
        __syncthreads();
    }
    float nb0 = nb[bn*64 + tc*4 + 0];
    float nb1 = nb[bn*64 + tc*4 + 1];
    float nb2 = nb[bn*64 + tc*4 + 2];
    float nb3 = nb[bn*64 + tc*4 + 3];
#pragma unroll
    for(int i=0;i<4;++i){
        int row = bm*64 + tr*4 + i;
        float nr = na[row];
        float4 o;
        o.x = nr + nb0 - 2.0f*acc[i][0];
        o.y = nr + nb1 - 2.0f*acc[i][1];
        o.z = nr + nb2 - 2.0f*acc[i][2];
        o.w = nr + nb3 - 2.0f*acc[i][3];
        *(float4*)(Cm + (size_t)row*N + bn*64 + tc*4) = o;
    }
}

// ---------------- global max of M = C - reg*log(P+eps) ----------------
__global__ __launch_bounds__(256) void maxM_k(const float* __restrict__ Cb,
                                              const float* __restrict__ Pb,
                                              float* __restrict__ maxsl, int slot, int iter0){
    int mat = blockIdx.y;
    const float4* C4 = (const float4*)(Cb + (size_t)mat*NM);
    const float4* P4 = (const float4*)(Pb + (size_t)mat*NM);
    const float lp0 = logf(P0CONST + EPSF);
    float m = -1e30f;
    int base = blockIdx.x*2048 + threadIdx.x;
#pragma unroll
    for(int k=0;k<8;++k){
        int i = base + k*256;
        float4 c = C4[i];
        float lx, ly, lz, lw;
        if(iter0){ lx=ly=lz=lw=lp0; }
        else {
            float4 p = P4[i];
            lx = logf(p.x+EPSF); ly = logf(p.y+EPSF);
            lz = logf(p.z+EPSF); lw = logf(p.w+EPSF);
        }
        m = fmaxf(m, c.x - REG*lx);
        m = fmaxf(m, c.y - REG*ly);
        m = fmaxf(m, c.z - REG*lz);
        m = fmaxf(m, c.w - REG*lw);
    }
    m = waveReduceMax(m);
    __shared__ float wmax[4];
    int w = threadIdx.x>>6, lane = threadIdx.x&63;
    if(lane==0) wmax[w] = m;
    __syncthreads();
    if(threadIdx.x==0){
        float bm = fmaxf(fmaxf(wmax[0],wmax[1]), fmaxf(wmax[2],wmax[3]));
        atomicMax((unsigned int*)(maxsl + mat*PROX + slot), __float_as_uint(bm)); // all M > 0
    }
}

// ---------------- K = exp(-(M/mx)/reg) ----------------
__global__ __launch_bounds__(256) void buildK_k(const float* __restrict__ Cb,
                                                const float* __restrict__ Pb,
                                                float* __restrict__ Kb,
                                                const float* __restrict__ maxsl, int slot, int iter0){
    int mat = blockIdx.y;
    size_t off = (size_t)mat*NM;
    int i = blockIdx.x*256 + threadIdx.x;
    float invmx = 1.0f / maxsl[mat*PROX + slot];
    const float lp0 = logf(P0CONST + EPSF);
    float4 c = ((const float4*)(Cb+off))[i];
    float lx, ly, lz, lw;
    if(iter0){ lx=ly=lz=lw=lp0; }
    else {
        float4 p = ((const float4*)(Pb+off))[i];
        lx = logf(p.x+EPSF); ly = logf(p.y+EPSF);
        lz = logf(p.z+EPSF); lw = logf(p.w+EPSF);
    }
    float4 k;
    k.x = expf((c.x - REG*lx) * invmx * -10.0f);
    k.y = expf((c.y - REG*ly) * invmx * -10.0f);
    k.z = expf((c.z - REG*lz) * invmx * -10.0f);
    k.w = expf((c.w - REG*lw) * invmx * -10.0f);
    ((float4*)(Kb+off))[i] = k;
}

// ---------------- KT = K^T (64x64 LDS tiles) ----------------
__global__ __launch_bounds__(256) void transp_k(const float* __restrict__ Kb,
                                                float* __restrict__ KTb){
    int mat = blockIdx.y; size_t off = (size_t)mat*NM;
    int tr = blockIdx.x >> 5, tc = blockIdx.x & 31;
    __shared__ float t[64][65];
#pragma unroll
    for(int i=0;i<4;++i){
        int id = threadIdx.x + 256*i;
        int r = id >> 4, c4 = id & 15;
        float4 v = *(const float4*)(Kb + off + (size_t)(tr*64+r)*N + tc*64 + c4*4);
        t[r][c4*4+0]=v.x; t[r][c4*4+1]=v.y; t[r][c4*4+2]=v.z; t[r][c4*4+3]=v.w;
    }
    __syncthreads();
#pragma unroll
    for(int i=0;i<4;++i){
        int id = threadIdx.x + 256*i;
        int r = id >> 4, c4 = id & 15;
        float4 v = { t[c4*4+0][r], t[c4*4+1][r], t[c4*4+2][r], t[c4*4+3][r] };
        *(float4*)(KTb + off + (size_t)(tc*64+r)*N + tr*64 + c4*4) = v;
    }
}

// ---------------- out[r] = (1/n) / (row_r(M) . u)  — the Sinkhorn half-step ----------------
__global__ __launch_bounds__(256) void mv_k(const float* __restrict__ Mb,
                                            const float* __restrict__ uvec,
                                            float* __restrict__ outv, int useConst){
    int mat = blockIdx.y;
    __shared__ float4 su[512];
    if(!useConst){
        const float4* u4 = (const float4*)(uvec + mat*N);
        su[threadIdx.x]     = u4[threadIdx.x];
        su[threadIdx.x+256] = u4[threadIdx.x+256];
    }
    __syncthreads();
    int w = threadIdx.x >> 6, lane = threadIdx.x & 63;
    int row = blockIdx.x*4 + w;
    const float4* r4 = (const float4*)(Mb + (size_t)mat*NM + (size_t)row*N);
    float s = 0.f;
    if(useConst){
#pragma unroll
        for(int i=0;i<8;++i){ float4 k = r4[lane + 64*i]; s += k.x+k.y+k.z+k.w; }
        s *= INV_N;
    } else {
#pragma unroll
        for(int i=0;i<8;++i){
            float4 k = r4[lane + 64*i];
            float4 u = su[lane + 64*i];
            s += k.x*u.x + k.y*u.y + k.z*u.z + k.w*u.w;
        }
    }
    s = waveReduceSum(s);
    if(lane==0) outv[mat*N + row] = INV_N / s;
}

// ---------------- P = u_i * K_ij * v_j ----------------
__global__ __launch_bounds__(256) void pbuild_k(const float* __restrict__ Kb,
                                                const float* __restrict__ u,
                                                const float* __restrict__ v,
                                                float* __restrict__ Pb){
    int mat = blockIdx.y; size_t off = (size_t)mat*NM;
    int i = blockIdx.x*256 + threadIdx.x;   // float4 index
    int row = i >> 9;                       // 512 float4 per row
    float uu = u[mat*N + row];
    float4 vv = ((const float4*)(v + mat*N))[i & 511];
    float4 k = ((const float4*)(Kb+off))[i];
    float4 p;
    p.x = uu*k.x*vv.x; p.y = uu*k.y*vv.y; p.z = uu*k.z*vv.z; p.w = uu*k.w*vv.w;
    ((float4*)(Pb+off))[i] = p;
}

// ---------------- column sums of normalized M (last prox iter: M_final) ----------------
__global__ __launch_bounds__(256) void colsumM_k(const float* __restrict__ Cb,
                                                 const float* __restrict__ Pb,
                                                 const float* __restrict__ maxsl, int slot,
                                                 float* __restrict__ colM){
    int mat = blockIdx.y;
    const float4* C4 = (const float4*)(Cb + (size_t)mat*NM);
    const float4* P4 = (const float4*)(Pb + (size_t)mat*NM);
    float invmx = 1.0f / maxsl[mat*PROX + slot];
    int r0 = blockIdx.x*32;
    float4 a0 = {0,0,0,0}, a1 = {0,0,0,0};
    for(int r=0;r<32;++r){
        int base = (r0 + r)*512;
        {
            float4 c = C4[base + threadIdx.x]; float4 p = P4[base + threadIdx.x];
            a0.x += (c.x - REG*logf(p.x+EPSF))*invmx;
            a0.y += (c.y - REG*logf(p.y+EPSF))*invmx;
            a0.z += (c.z - REG*logf(p.z+EPSF))*invmx;
            a0.w += (c.w - REG*logf(p.w+EPSF))*invmx;
        }
        {
            float4 c = C4[base + 256 + threadIdx.x]; float4 p = P4[base + 256 + threadIdx.x];
            a1.x += (c.x - REG*logf(p.x+EPSF))*invmx;
            a1.y += (c.y - REG*logf(p.y+EPSF))*invmx;
            a1.z += (c.z - REG*logf(p.z+EPSF))*invmx;
            a1.w += (c.w - REG*logf(p.w+EPSF))*invmx;
        }
    }
    float* cm = colM + mat*N;
    atomicAdd(cm + 4*threadIdx.x + 0, a0.x);
    atomicAdd(cm + 4*threadIdx.x + 1, a0.y);
    atomicAdd(cm + 4*threadIdx.x + 2, a0.z);
    atomicAdd(cm + 4*threadIdx.x + 3, a0.w);
    atomicAdd(cm + 1024 + 4*threadIdx.x + 0, a1.x);
    atomicAdd(cm + 1024 + 4*threadIdx.x + 1, a1.y);
    atomicAdd(cm + 1024 + 4*threadIdx.x + 2, a1.z);
    atomicAdd(cm + 1024 + 4*threadIdx.x + 3, a1.w);
}

// ---------------- column sums of T and of log(T+eps) ----------------
__global__ __launch_bounds__(256) void colsumTL_k(const float* __restrict__ Pb,
                                                  float* __restrict__ colT,
                                                  float* __restrict__ colL){
    int mat = blockIdx.y;
    const float4* P4 = (const float4*)(Pb + (size_t)mat*NM);
    int r0 = blockIdx.x*32;
    float4 t0 = {0,0,0,0}, t1 = {0,0,0,0};
    float4 l0 = {0,0,0,0}, l1 = {0,0,0,0};
    for(int r=0;r<32;++r){
        int base = (r0 + r)*512;
        {
            float4 p = P4[base + threadIdx.x];
            t0.x += p.x; t0.y += p.y; t0.z += p.z; t0.w += p.w;
            l0.x += logf(p.x+EPSF); l0.y += logf(p.y+EPSF);
            l0.z += logf(p.z+EPSF); l0.w += logf(p.w+EPSF);
        }
        {
            float4 p = P4[base + 256 + threadIdx.x];
            t1.x += p.x; t1.y += p.y; t1.z += p.z; t1.w += p.w;
            l1.x += logf(p.x+EPSF); l1.y += logf(p.y+EPSF);
            l1.z += logf(p.z+EPSF); l1.w += logf(p.w+EPSF);
        }
    }
    float* ct = colT + mat*N;
    float* cl = colL + mat*N;
    atomicAdd(ct + 4*threadIdx.x + 0, t0.x);
    atomicAdd(ct + 4*threadIdx.x + 1, t0.y);
    atomicAdd(ct + 4*threadIdx.x + 2, t0.z);
    atomicAdd(ct + 4*threadIdx.x + 3, t0.w);
    atomicAdd(ct + 1024 + 4*threadIdx.x + 0, t1.x);
    atomicAdd(ct + 1024 + 4*threadIdx.x + 1, t1.y);
    atomicAdd(ct + 1024 + 4*threadIdx.x + 2, t1.z);
    atomicAdd(ct + 1024 + 4*threadIdx.x + 3, t1.w);
    atomicAdd(cl + 4*threadIdx.x + 0, l0.x);
    atomicAdd(cl + 4*threadIdx.x + 1, l0.y);
    atomicAdd(cl + 4*threadIdx.x + 2, l0.z);
    atomicAdd(cl + 4*threadIdx.x + 3, l0.w);
    atomicAdd(cl + 1024 + 4*threadIdx.x + 0, l1.x);
    atomicAdd(cl + 1024 + 4*threadIdx.x + 1, l1.y);
    atomicAdd(cl + 1024 + 4*threadIdx.x + 2, l1.z);
    atomicAdd(cl + 1024 + 4*threadIdx.x + 3, l1.w);
}

// ---------------- final: div_mean = (1/n^2)(colT.colM + reg*colT.(colL - n)); combine ------
__global__ __launch_bounds__(256) void final_k(const float* __restrict__ colM,
                                               const float* __restrict__ colT,
                                               const float* __restrict__ colL,
                                               float* __restrict__ out){
    __shared__ float red[8];
    __shared__ float divs[3];
    for(int mat=0; mat<3; ++mat){
        float s1=0.f, s2=0.f;
        for(int j=threadIdx.x; j<N; j+=256){
            float t = colT[mat*N+j];
            s1 += t * colM[mat*N+j];
            s2 += t * (colL[mat*N+j] - (float)N);
        }
        s1 = waveReduceSum(s1); s2 = waveReduceSum(s2);
        int w = threadIdx.x>>6, lane = threadIdx.x&63;
        if(lane==0){ red[w] = s1; red[4+w] = s2; }
        __syncthreads();
        if(threadIdx.x==0){
            float a = red[0]+red[1]+red[2]+red[3];
            float b = red[4]+red[5]+red[6]+red[7];
            divs[mat] = (a + REG*b) * (1.0f/((float)N*(float)N));
        }
        __syncthreads();
    }
    if(threadIdx.x==0) out[0] = divs[1] - 0.5f*(divs[0] + divs[2]);
}

extern "C" void kernel_launch(void* const* d_in, const int* in_sizes, int n_in,
                              void* d_out, int out_size, void* d_ws, size_t ws_size,
                              hipStream_t stream){
    const float* x = (const float*)d_in[0];
    const float* y = (const float*)d_in[1];
    float* ws = (float*)d_ws;
    // layout (floats): C[3*NM] K[3*NM] KT[3*NM] P[3*NM] u[3N] v[3N] nx[N] ny[N]
    //                  maxsl[16] colM[3N] colT[3N] colL[3N]   (~192.1 MiB total)
    float* C     = ws;
    float* K     = ws + (size_t)3*NM;
    float* KT    = ws + (size_t)6*NM;
    float* P     = ws + (size_t)9*NM;
    float* u     = ws + (size_t)12*NM;
    float* v     = u + 3*N;
    float* nx    = v + 3*N;
    float* ny    = nx + N;
    float* zb    = ny + N;           // zero-initialized region
    float* maxsl = zb;               // 16 slots (15 used)
    float* colM  = zb + 16;
    float* colT  = colM + 3*N;
    float* colL  = colT + 3*N;
    size_t zbytes = (16 + (size_t)9*N)*sizeof(float);
    hipMemsetAsync(zb, 0, zbytes, stream);

    norms_k <<<dim3(512,2), 256, 0, stream>>>(x, y, nx, ny);
    sqdist_k<<<dim3(1024,3),256, 0, stream>>>(x, y, nx, ny, C);

    for(int t=0; t<PROX; ++t){
        maxM_k  <<<dim3(512,3), 256, 0, stream>>>(C, P, maxsl, t, t==0);
        buildK_k<<<dim3(4096,3),256, 0, stream>>>(C, P, K, maxsl, t, t==0);
        transp_k<<<dim3(1024,3),256, 0, stream>>>(K, KT);
        for(int it=0; it<SINK; ++it){
            mv_k<<<dim3(512,3), 256, 0, stream>>>(KT, u, v, it==0); // v = q/(K^T u)
            mv_k<<<dim3(512,3), 256, 0, stream>>>(K,  v, u, 0);     // u = p/(K v)
        }
        mv_k<<<dim3(512,3), 256, 0, stream>>>(KT, u, v, 0);          // final v
        if(t==PROX-1)
            colsumM_k<<<dim3(64,3), 256, 0, stream>>>(C, P, maxsl, t, colM); // uses P4 (= T_pre)
        pbuild_k<<<dim3(4096,3),256, 0, stream>>>(K, u, v, P);
    }
    colsumTL_k<<<dim3(64,3), 256, 0, stream>>>(P, colT, colL);
    final_k   <<<1, 256, 0, stream>>>(colM, colT, colL, (float*)d_out);
}

// Round 2
// 4999.365 us; speedup vs baseline: 1.8896x; 1.8896x over previous
//
#include <hip/hip_runtime.h>
#include <hip/hip_fp16.h>
#include <math.h>

#define N 2048
#define D 256
#define NM (N*N)            // 4194304 elements per matrix
#define REG 0.1f
#define EPSF 1e-10f
#define INV_N (1.0f/2048.0f)
#define P0CONST (1.0f/(2048.0f*2048.0f))
#define PROX 5
#define SINK 100
#define KSCALE 256.0f       // cancels exactly in Sinkhorn (u, P invariant)
#define MV_NBLK 512         // blocks per matrix in mv grid

__device__ __forceinline__ float waveReduceSum(float v){
#pragma unroll
    for(int o=32;o;o>>=1) v += __shfl_xor(v,o,64);
    return v;
}
__device__ __forceinline__ float waveReduceMax(float v){
#pragma unroll
    for(int o=32;o;o>>=1) v = fmaxf(v, __shfl_xor(v,o,64));
    return v;
}

// ---------------- row squared-norms of x and y ----------------
__global__ __launch_bounds__(256) void norms_k(const float* __restrict__ x,
                                               const float* __restrict__ y,
                                               float* __restrict__ nx,
                                               float* __restrict__ ny){
    const float* src = blockIdx.y ? y : x;
    float* dst       = blockIdx.y ? ny : nx;
    int w = threadIdx.x >> 6, lane = threadIdx.x & 63;
    int row = blockIdx.x*4 + w;
    const float4* r4 = (const float4*)(src + (size_t)row*D);
    float4 f = r4[lane];
    float s = f.x*f.x + f.y*f.y + f.z*f.z + f.w*f.w;
    s = waveReduceSum(s);
    if(lane==0) dst[row] = s;
}

// ---------------- C = |a_i|^2 + |b_j|^2 - 2 a_i.b_j  (3 matrices via blockIdx.y) --------
// NOTE: accumulation order identical for (i,j) and (j,i) -> C_xx, C_yy bitwise symmetric.
__global__ __launch_bounds__(256) void sqdist_k(const float* __restrict__ x,
                                                const float* __restrict__ y,
                                                const float* __restrict__ nx,
                                                const float* __restrict__ ny,
                                                float* __restrict__ Cb){
    int mat = blockIdx.y;
    const float* A  = (mat<2)  ? x  : y;
    const float* B  = (mat==0) ? x  : y;
    const float* na = (mat<2)  ? nx : ny;
    const float* nb = (mat==0) ? nx : ny;
    float* Cm = Cb + (size_t)mat*NM;
    int bm = blockIdx.x >> 5, bn = blockIdx.x & 31;
    __shared__ float As[32][68];
    __shared__ float Bs[32][68];
    int tid = threadIdx.x;
    int tr = tid >> 4, tc = tid & 15;
    float acc[4][4] = {};
    for(int kb=0; kb<8; ++kb){
#pragma unroll
        for(int i=0;i<2;++i){
            int id = tid + 256*i;
            int r = id >> 3, c4 = id & 7;
            float4 a = *(const float4*)(A + (size_t)(bm*64 + r)*D + kb*32 + c4*4);
            As[c4*4+0][r]=a.x; As[c4*4+1][r]=a.y; As[c4*4+2][r]=a.z; As[c4*4+3][r]=a.w;
            float4 b = *(const float4*)(B + (size_t)(bn*64 + r)*D + kb*32 + c4*4);
            Bs[c4*4+0][r]=b.x; Bs[c4*4+1][r]=b.y; Bs[c4*4+2][r]=b.z; Bs[c4*4+3][r]=b.w;
        }
        __syncthreads();
#pragma unroll
        for(int d=0; d<32; ++d){
            float4 a = *(const float4*)&As[d][4*tr];
            float4 b = *(const float4*)&Bs[d][4*tc];
            acc[0][0] += a.x*b.x; acc[0][1] += a.x*b.y; acc[0][2] += a.x*b.z; acc[0][3] += a.x*b.w;
            acc[1][0] += a.y*b.x; acc[1][1] += a.y*b.y; acc[1][2] += a.y*b.z; acc[1][3] += a.y*b.w;
            acc[2][0] += a.z*b.x; acc[2][1] += a.z*b.y; acc[2][2] += a.z*b.z; acc[2][3] += a.z*b.w;
            acc[3][0] += a.w*b.x; acc[3][1] += a.w*b.y; acc[3][2] += a.w*b.z; acc[3][3] += a.w*b.w;
        }
        __syncthreads();
    }
    float nb0 = nb[bn*64 + tc*4 + 0];
    float nb1 = nb[bn*64 + tc*4 + 1];
    float nb2 = nb[bn*64 + tc*4 + 2];
    float nb3 = nb[bn*64 + tc*4 + 3];
#pragma unroll
    for(int i=0;i<4;++i){
        int row = bm*64 + tr*4 + i;
        float nr = na[row];
        float4 o;
        o.x = nr + nb0 - 2.0f*acc[i][0];
        o.y = nr + nb1 - 2.0f*acc[i][1];
        o.z = nr + nb2 - 2.0f*acc[i][2];
        o.w = nr + nb3 - 2.0f*acc[i][3];
        *(float4*)(Cm + (size_t)row*N + bn*64 + tc*4) = o;
    }
}

// ---------------- global max of M = C - reg*log(P+eps) ----------------
__global__ __launch_bounds__(256) void maxM_k(const float* __restrict__ Cb,
                                              const float* __restrict__ Pb,
                                              float* __restrict__ maxsl, int slot, int iter0){
    int mat = blockIdx.y;
    const float4* C4 = (const float4*)(Cb + (size_t)mat*NM);
    const float4* P4 = (const float4*)(Pb + (size_t)mat*NM);
    const float lp0 = logf(P0CONST + EPSF);
    float m = -1e30f;
    int base = blockIdx.x*2048 + threadIdx.x;
#pragma unroll
    for(int k=0;k<8;++k){
        int i = base + k*256;
        float4 c = C4[i];
        float lx, ly, lz, lw;
        if(iter0){ lx=ly=lz=lw=lp0; }
        else {
            float4 p = P4[i];
            lx = logf(p.x+EPSF); ly = logf(p.y+EPSF);
            lz = logf(p.z+EPSF); lw = logf(p.w+EPSF);
        }
        m = fmaxf(m, c.x - REG*lx);
        m = fmaxf(m, c.y - REG*ly);
        m = fmaxf(m, c.z - REG*lz);
        m = fmaxf(m, c.w - REG*lw);
    }
    m = waveReduceMax(m);
    __shared__ float wmax[4];
    int w = threadIdx.x>>6, lane = threadIdx.x&63;
    if(lane==0) wmax[w] = m;
    __syncthreads();
    if(threadIdx.x==0){
        float bm = fmaxf(fmaxf(wmax[0],wmax[1]), fmaxf(wmax[2],wmax[3]));
        atomicMax((unsigned int*)(maxsl + mat*PROX + slot), __float_as_uint(bm)); // all M > 0
    }
}

// ---------------- K' = KSCALE * exp(-(M/mx)/reg) as fp16; fused transpose for xy --------
// grid (1024,3): 32x32 tiles of 64x64. For mat==1 also writes KT'_xy via LDS transpose.
__global__ __launch_bounds__(256) void buildK_k(const float* __restrict__ Cb,
                                                const float* __restrict__ Pb,
                                                __half* __restrict__ Kh,
                                                __half* __restrict__ KTh,
                                                const float* __restrict__ maxsl,
                                                int slot, int iter0){
    int mat = blockIdx.y;
    size_t off = (size_t)mat*NM;
    int br = blockIdx.x >> 5, bc = blockIdx.x & 31;
    float invmx = 1.0f / maxsl[mat*PROX + slot];
    const float lp0 = logf(P0CONST + EPSF);
    __shared__ float tf[64][65];
    int r  = threadIdx.x >> 2;
    int c0 = (threadIdx.x & 3) * 16;
    size_t rowbase = off + (size_t)(br*64 + r)*N + bc*64 + c0;
    __half hv[16];
#pragma unroll
    for(int k=0;k<16;k+=4){
        float4 c4 = *(const float4*)(Cb + rowbase + k);
        float lx,ly,lz,lw;
        if(iter0){ lx=ly=lz=lw=lp0; }
        else {
            float4 p4 = *(const float4*)(Pb + rowbase + k);
            lx = logf(p4.x+EPSF); ly = logf(p4.y+EPSF);
            lz = logf(p4.z+EPSF); lw = logf(p4.w+EPSF);
        }
        float k0 = KSCALE*expf((c4.x - REG*lx)*invmx*-10.0f);
        float k1 = KSCALE*expf((c4.y - REG*ly)*invmx*-10.0f);
        float k2 = KSCALE*expf((c4.z - REG*lz)*invmx*-10.0f);
        float k3 = KSCALE*expf((c4.w - REG*lw)*invmx*-10.0f);
        hv[k+0]=__float2half(k0); hv[k+1]=__float2half(k1);
        hv[k+2]=__float2half(k2); hv[k+3]=__float2half(k3);
        if(mat==1){ tf[r][c0+k]=k0; tf[r][c0+k+1]=k1; tf[r][c0+k+2]=k2; tf[r][c0+k+3]=k3; }
    }
    *(float4*)(&Kh[rowbase])     = *(float4*)(&hv[0]);
    *(float4*)(&Kh[rowbase + 8]) = *(float4*)(&hv[8]);
    if(mat==1){
        __syncthreads();
        __half ht[16];
#pragma unroll
        for(int k=0;k<16;++k) ht[k] = __float2half(tf[c0+k][r]);
        size_t tbase = (size_t)(bc*64 + r)*N + br*64 + c0;
        *(float4*)(&KTh[tbase])     = *(float4*)(&ht[0]);
        *(float4*)(&KTh[tbase + 8]) = *(float4*)(&ht[8]);
    }
}

// ---------------- out[r] = (1/n) / (row_r(K') . u)  — Sinkhorn half-step, fp16 K --------
// Early-exit: conv[mat] latches (per prox) when the previous u-update was a bitwise
// fixpoint for all rows -> all remaining iterations are exactly idempotent.
__global__ __launch_bounds__(256) void mv_k(const __half* __restrict__ Kxx,
                                            const __half* __restrict__ Kxyd,
                                            const __half* __restrict__ Kyy,
                                            const float* __restrict__ uvec,
                                            float* __restrict__ outv, int useConst,
                                            const int* __restrict__ cntPrev,
                                            int* __restrict__ cntMine,
                                            int* __restrict__ conv){
    int mat = blockIdx.y;
    if(conv[mat]) return;
    if(cntPrev && cntPrev[mat] == MV_NBLK){
        if(threadIdx.x==0) conv[mat] = 1;
        return;
    }
    const __half* Kp = (mat==0) ? Kxx : ((mat==1) ? Kxyd : Kyy);
    __shared__ float su[2048];
    __shared__ int vote;
    if(threadIdx.x==0) vote = 1;
    if(!useConst){
        float4* s4 = (float4*)su;
        const float4* u4 = (const float4*)(uvec + mat*N);
        s4[threadIdx.x]     = u4[threadIdx.x];
        s4[threadIdx.x+256] = u4[threadIdx.x+256];
    }
    __syncthreads();
    int w = threadIdx.x >> 6, lane = threadIdx.x & 63;
    int row = blockIdx.x*4 + w;
    const float4* r4 = (const float4*)(Kp + (size_t)row*N);   // 256 float4 (8 halves each)
    float s = 0.f;
    if(useConst){
#pragma unroll
        for(int i=0;i<4;++i){
            float4 b = r4[lane + 64*i];
            const __half2* h2 = (const __half2*)&b;
            float2 f0=__half22float2(h2[0]), f1=__half22float2(h2[1]);
            float2 f2=__half22float2(h2[2]), f3=__half22float2(h2[3]);
            s += f0.x+f0.y+f1.x+f1.y+f2.x+f2.y+f3.x+f3.y;
        }
        s *= INV_N;
    } else {
#pragma unroll
        for(int i=0;i<4;++i){
            float4 b = r4[lane + 64*i];
            const __half2* h2 = (const __half2*)&b;
            float2 f0=__half22float2(h2[0]), f1=__half22float2(h2[1]);
            float2 f2=__half22float2(h2[2]), f3=__half22float2(h2[3]);
            int j = (lane + 64*i)*8;
            s += f0.x*su[j]   + f0.y*su[j+1] + f1.x*su[j+2] + f1.y*su[j+3]
               + f2.x*su[j+4] + f2.y*su[j+5] + f3.x*su[j+6] + f3.y*su[j+7];
        }
    }
    s = waveReduceSum(s);
    float newv = INV_N / s;
    if(lane==0){
        float oldv = outv[mat*N + row];
        outv[mat*N + row] = newv;
        if(cntMine && __float_as_uint(newv) != __float_as_uint(oldv)) vote = 0;
    }
    if(cntMine){
        __syncthreads();
        if(threadIdx.x==0 && vote) atomicAdd(&cntMine[mat], 1);
    }
}

// ---------------- P = u_i * K'_ij * v'_j  (scale cancels: K'=s*K, v'=v/s) ----------------
__global__ __launch_bounds__(256) void pbuild_k(const __half* __restrict__ Kh,
                                                const float* __restrict__ u,
                                                const float* __restrict__ v,
                                                float* __restrict__ Pb){
    int mat = blockIdx.y; size_t off = (size_t)mat*NM;
    int i4 = blockIdx.x*256 + threadIdx.x;   // index of 8-half packet
    int row = i4 >> 8;                       // 256 packets per row
    int j = (i4 & 255)*8;
    float uu = u[mat*N + row];
    float4 b = ((const float4*)(Kh + off))[i4];
    const __half2* h2 = (const __half2*)&b;
    float2 f0=__half22float2(h2[0]), f1=__half22float2(h2[1]);
    float2 f2=__half22float2(h2[2]), f3=__half22float2(h2[3]);
    const float4* v4 = (const float4*)(v + mat*N + j);
    float4 va = v4[0], vb = v4[1];
    float4 o0, o1;
    o0.x = uu*f0.x*va.x; o0.y = uu*f0.y*va.y; o0.z = uu*f1.x*va.z; o0.w = uu*f1.y*va.w;
    o1.x = uu*f2.x*vb.x; o1.y = uu*f2.y*vb.y; o1.z = uu*f3.x*vb.z; o1.w = uu*f3.y*vb.w;
    float4* out4 = (float4*)(Pb + off);
    out4[i4*2]   = o0;
    out4[i4*2+1] = o1;
}

// ---------------- column sums of normalized M (last prox iter: M_final) ----------------
__global__ __launch_bounds__(256) void colsumM_k(const float* __restrict__ Cb,
                                                 const float* __restrict__ Pb,
                                                 const float* __restrict__ maxsl, int slot,
                                                 float* __restrict__ colM){
    int mat = blockIdx.y;
    const float4* C4 = (const float4*)(Cb + (size_t)mat*NM);
    const float4* P4 = (const float4*)(Pb + (size_t)mat*NM);
    float invmx = 1.0f / maxsl[mat*PROX + slot];
    int r0 = blockIdx.x*32;
    float4 a0 = {0,0,0,0}, a1 = {0,0,0,0};
    for(int r=0;r<32;++r){
        int base = (r0 + r)*512;
        {
            float4 c = C4[base + threadIdx.x]; float4 p = P4[base + threadIdx.x];
            a0.x += (c.x - REG*logf(p.x+EPSF))*invmx;
            a0.y += (c.y - REG*logf(p.y+EPSF))*invmx;
            a0.z += (c.z - REG*logf(p.z+EPSF))*invmx;
            a0.w += (c.w - REG*logf(p.w+EPSF))*invmx;
        }
        {
            float4 c = C4[base + 256 + threadIdx.x]; float4 p = P4[base + 256 + threadIdx.x];
            a1.x += (c.x - REG*logf(p.x+EPSF))*invmx;
            a1.y += (c.y - REG*logf(p.y+EPSF))*invmx;
            a1.z += (c.z - REG*logf(p.z+EPSF))*invmx;
            a1.w += (c.w - REG*logf(p.w+EPSF))*invmx;
        }
    }
    float* cm = colM + mat*N;
    atomicAdd(cm + 4*threadIdx.x + 0, a0.x);
    atomicAdd(cm + 4*threadIdx.x + 1, a0.y);
    atomicAdd(cm + 4*threadIdx.x + 2, a0.z);
    atomicAdd(cm + 4*threadIdx.x + 3, a0.w);
    atomicAdd(cm + 1024 + 4*threadIdx.x + 0, a1.x);
    atomicAdd(cm + 1024 + 4*threadIdx.x + 1, a1.y);
    atomicAdd(cm + 1024 + 4*threadIdx.x + 2, a1.z);
    atomicAdd(cm + 1024 + 4*threadIdx.x + 3, a1.w);
}

// ---------------- column sums of T and of log(T+eps) ----------------
__global__ __launch_bounds__(256) void colsumTL_k(const float* __restrict__ Pb,
                                                  float* __restrict__ colT,
                                                  float* __restrict__ colL){
    int mat = blockIdx.y;
    const float4* P4 = (const float4*)(Pb + (size_t)mat*NM);
    int r0 = blockIdx.x*32;
    float4 t0 = {0,0,0,0}, t1 = {0,0,0,0};
    float4 l0 = {0,0,0,0}, l1 = {0,0,0,0};
    for(int r=0;r<32;++r){
        int base = (r0 + r)*512;
        {
            float4 p = P4[base + threadIdx.x];
            t0.x += p.x; t0.y += p.y; t0.z += p.z; t0.w += p.w;
            l0.x += logf(p.x+EPSF); l0.y += logf(p.y+EPSF);
            l0.z += logf(p.z+EPSF); l0.w += logf(p.w+EPSF);
        }
        {
            float4 p = P4[base + 256 + threadIdx.x];
            t1.x += p.x; t1.y += p.y; t1.z += p.z; t1.w += p.w;
            l1.x += logf(p.x+EPSF); l1.y += logf(p.y+EPSF);
            l1.z += logf(p.z+EPSF); l1.w += logf(p.w+EPSF);
        }
    }
    float* ct = colT + mat*N;
    float* cl = colL + mat*N;
    atomicAdd(ct + 4*threadIdx.x + 0, t0.x);
    atomicAdd(ct + 4*threadIdx.x + 1, t0.y);
    atomicAdd(ct + 4*threadIdx.x + 2, t0.z);
    atomicAdd(ct + 4*threadIdx.x + 3, t0.w);
    atomicAdd(ct + 1024 + 4*threadIdx.x + 0, t1.x);
    atomicAdd(ct + 1024 + 4*threadIdx.x + 1, t1.y);
    atomicAdd(ct + 1024 + 4*threadIdx.x + 2, t1.z);
    atomicAdd(ct + 1024 + 4*threadIdx.x + 3, t1.w);
    atomicAdd(cl + 4*threadIdx.x + 0, l0.x);
    atomicAdd(cl + 4*threadIdx.x + 1, l0.y);
    atomicAdd(cl + 4*threadIdx.x + 2, l0.z);
    atomicAdd(cl + 4*threadIdx.x + 3, l0.w);
    atomicAdd(cl + 1024 + 4*threadIdx.x + 0, l1.x);
    atomicAdd(cl + 1024 + 4*threadIdx.x + 1, l1.y);
    atomicAdd(cl + 1024 + 4*threadIdx.x + 2, l1.z);
    atomicAdd(cl + 1024 + 4*threadIdx.x + 3, l1.w);
}

// ---------------- final: div_mean = (1/n^2)(colT.colM + reg*colT.(colL - n)); combine ----
__global__ __launch_bounds__(256) void final_k(const float* __restrict__ colM,
                                               const float* __restrict__ colT,
                                               const float* __restrict__ colL,
                                               float* __restrict__ out){
    __shared__ float red[8];
    __shared__ float divs[3];
    for(int mat=0; mat<3; ++mat){
        float s1=0.f, s2=0.f;
        for(int j=threadIdx.x; j<N; j+=256){
            float t = colT[mat*N+j];
            s1 += t * colM[mat*N+j];
            s2 += t * (colL[mat*N+j] - (float)N);
        }
        s1 = waveReduceSum(s1); s2 = waveReduceSum(s2);
        int w = threadIdx.x>>6, lane = threadIdx.x&63;
        if(lane==0){ red[w] = s1; red[4+w] = s2; }
        __syncthreads();
        if(threadIdx.x==0){
            float a = red[0]+red[1]+red[2]+red[3];
            float b = red[4]+red[5]+red[6]+red[7];
            divs[mat] = (a + REG*b) * (1.0f/((float)N*(float)N));
        }
        __syncthreads();
    }
    if(threadIdx.x==0) out[0] = divs[1] - 0.5f*(divs[0] + divs[2]);
}

extern "C" void kernel_launch(void* const* d_in, const int* in_sizes, int n_in,
                              void* d_out, int out_size, void* d_ws, size_t ws_size,
                              hipStream_t stream){
    const float* x = (const float*)d_in[0];
    const float* y = (const float*)d_in[1];
    float* ws = (float*)d_ws;
    // layout: C[3NM] P[3NM] f32 | Kh[3NM] KTh[NM] f16 | u,v,nx,ny | zeroed tail
    float*  C    = ws;
    float*  P    = C + (size_t)3*NM;
    __half* Kh   = (__half*)(P + (size_t)3*NM);
    __half* KTh  = Kh + (size_t)3*NM;
    float*  u    = (float*)(KTh + (size_t)NM);
    float*  v    = u + 3*N;
    float*  nx   = v + 3*N;
    float*  ny   = nx + N;
    float*  zb   = ny + N;
    float*  maxsl= zb;                 // 16 floats
    float*  colM = zb + 16;            // 3N
    float*  colT = colM + 3*N;         // 3N
    float*  colL = colT + 3*N;         // 3N
    int*    conv = (int*)(colL + 3*N); // 16 ints (5 prox x 3 used)
    int*    cnt  = conv + 16;          // 5*100*3 = 1500 ints
    size_t zbytes = (16 + (size_t)9*N)*sizeof(float) + (16 + 1500)*sizeof(int);
    hipMemsetAsync(zb, 0, zbytes, stream);

    norms_k <<<dim3(512,2), 256, 0, stream>>>(x, y, nx, ny);
    sqdist_k<<<dim3(1024,3),256, 0, stream>>>(x, y, nx, ny, C);

    const __half* Kxx = Kh;
    const __half* Kxy = Kh + (size_t)NM;
    const __half* Kyy = Kh + (size_t)2*NM;

    for(int t=0; t<PROX; ++t){
        maxM_k  <<<dim3(512,3), 256, 0, stream>>>(C, P, maxsl, t, t==0);
        buildK_k<<<dim3(1024,3),256, 0, stream>>>(C, P, Kh, KTh, maxsl, t, t==0);
        int* convT = conv + t*3;
        int* cntT  = cnt + t*300;
        for(int it=0; it<SINK; ++it){
            // v-step: v = q/(K^T u); K_xx, K_yy symmetric -> use K itself
            mv_k<<<dim3(MV_NBLK,3), 256, 0, stream>>>(Kxx, KTh, Kyy, u, v, it==0,
                    (it>0) ? (cntT + (it-1)*3) : (const int*)nullptr, nullptr, convT);
            // u-step: u = p/(K v); votes convergence
            mv_k<<<dim3(MV_NBLK,3), 256, 0, stream>>>(Kxx, Kxy, Kyy, v, u, 0,
                    nullptr, cntT + it*3, convT);
        }
        // final v
        mv_k<<<dim3(MV_NBLK,3), 256, 0, stream>>>(Kxx, KTh, Kyy, u, v, 0,
                cntT + 99*3, nullptr, convT);
        if(t==PROX-1)
            colsumM_k<<<dim3(64,3), 256, 0, stream>>>(C, P, maxsl, t, colM); // P = T_pre
        pbuild_k<<<dim3(2048,3),256, 0, stream>>>(Kh, u, v, P);
    }
    colsumTL_k<<<dim3(64,3), 256, 0, stream>>>(P, colT, colL);
    final_k   <<<1, 256, 0, stream>>>(colM, colT, colL, (float*)d_out);
}

// Round 3
// 4031.982 us; speedup vs baseline: 2.3430x; 1.2399x over previous
//
#include <hip/hip_runtime.h>
#include <hip/hip_fp16.h>
#include <math.h>

#define N 2048
#define D 256
#define NM (N*N)
#define REG 0.1f
#define EPSF 1e-10f
#define INV_N (1.0f/2048.0f)
#define P0CONST (1.0f/(2048.0f*2048.0f))
#define PROX 5
#define SINK 100
#define KSCALE 256.0f       // cancels exactly in Sinkhorn (u, P invariant)
#define TOL 1e-6f
#define SMEM_BYTES (131072 + 256)

__device__ __forceinline__ float waveReduceSum(float v){
#pragma unroll
    for(int o=32;o;o>>=1) v += __shfl_xor(v,o,64);
    return v;
}
__device__ __forceinline__ float waveReduceMax(float v){
#pragma unroll
    for(int o=32;o;o>>=1) v = fmaxf(v, __shfl_xor(v,o,64));
    return v;
}

// lane-contiguous LDS swizzle: column c (0..2047) -> half-index within row.
// ds_read_b128 instr i, lane l then reads a contiguous 1KB block (bank-optimal);
// lane l still owns columns [l*32, l*32+32).
__device__ __forceinline__ int swz(int c){
    return ((c>>3)&3)*512 + ((c>>5)<<3) + (c&7);
}

// ---------------- row squared-norms of x and y ----------------
__global__ __launch_bounds__(256) void norms_k(const float* __restrict__ x,
                                               const float* __restrict__ y,
                                               float* __restrict__ nx,
                                               float* __restrict__ ny){
    const float* src = blockIdx.y ? y : x;
    float* dst       = blockIdx.y ? ny : nx;
    int w = threadIdx.x >> 6, lane = threadIdx.x & 63;
    int row = blockIdx.x*4 + w;
    const float4* r4 = (const float4*)(src + (size_t)row*D);
    float4 f = r4[lane];
    float s = f.x*f.x + f.y*f.y + f.z*f.z + f.w*f.w;
    s = waveReduceSum(s);
    if(lane==0) dst[row] = s;
}

// ---------------- C = |a_i|^2 + |b_j|^2 - 2 a_i.b_j  (3 matrices) --------
// accumulation order identical for (i,j)/(j,i) -> C_xx, C_yy bitwise symmetric.
__global__ __launch_bounds__(256) void sqdist_k(const float* __restrict__ x,
                                                const float* __restrict__ y,
                                                const float* __restrict__ nx,
                                                const float* __restrict__ ny,
                                                float* __restrict__ Cb){
    int mat = blockIdx.y;
    const float* A  = (mat<2)  ? x  : y;
    const float* B  = (mat==0) ? x  : y;
    const float* na = (mat<2)  ? nx : ny;
    const float* nb = (mat==0) ? nx : ny;
    float* Cm = Cb + (size_t)mat*NM;
    int bm = blockIdx.x >> 5, bn = blockIdx.x & 31;
    __shared__ float As[32][68];
    __shared__ float Bs[32][68];
    int tid = threadIdx.x;
    int tr = tid >> 4, tc = tid & 15;
    float acc[4][4] = {};
    for(int kb=0; kb<8; ++kb){
#pragma unroll
        for(int i=0;i<2;++i){
            int id = tid + 256*i;
            int r = id >> 3, c4 = id & 7;
            float4 a = *(const float4*)(A + (size_t)(bm*64 + r)*D + kb*32 + c4*4);
            As[c4*4+0][r]=a.x; As[c4*4+1][r]=a.y; As[c4*4+2][r]=a.z; As[c4*4+3][r]=a.w;
            float4 b = *(const float4*)(B + (size_t)(bn*64 + r)*D + kb*32 + c4*4);
            Bs[c4*4+0][r]=b.x; Bs[c4*4+1][r]=b.y; Bs[c4*4+2][r]=b.z; Bs[c4*4+3][r]=b.w;
        }
        __syncthreads();
#pragma unroll
        for(int d=0; d<32; ++d){
            float4 a = *(const float4*)&As[d][4*tr];
            float4 b = *(const float4*)&Bs[d][4*tc];
            acc[0][0] += a.x*b.x; acc[0][1] += a.x*b.y; acc[0][2] += a.x*b.z; acc[0][3] += a.x*b.w;
            acc[1][0] += a.y*b.x; acc[1][1] += a.y*b.y; acc[1][2] += a.y*b.z; acc[1][3] += a.y*b.w;
            acc[2][0] += a.z*b.x; acc[2][1] += a.z*b.y; acc[2][2] += a.z*b.z; acc[2][3] += a.z*b.w;
            acc[3][0] += a.w*b.x; acc[3][1] += a.w*b.y; acc[3][2] += a.w*b.z; acc[3][3] += a.w*b.w;
        }
        __syncthreads();
    }
    float nb0 = nb[bn*64 + tc*4 + 0];
    float nb1 = nb[bn*64 + tc*4 + 1];
    float nb2 = nb[bn*64 + tc*4 + 2];
    float nb3 = nb[bn*64 + tc*4 + 3];
#pragma unroll
    for(int i=0;i<4;++i){
        int row = bm*64 + tr*4 + i;
        float nr = na[row];
        float4 o;
        o.x = nr + nb0 - 2.0f*acc[i][0];
        o.y = nr + nb1 - 2.0f*acc[i][1];
        o.z = nr + nb2 - 2.0f*acc[i][2];
        o.w = nr + nb3 - 2.0f*acc[i][3];
        *(float4*)(Cm + (size_t)row*N + bn*64 + tc*4) = o;
    }
}

// ================= persistent cooperative kernel: full 3-chain prox-Sinkhorn =============
// 256 blocks x 1024 threads, 1 block/CU. Blocks 0-63: xx (32 rows), 64-127: yy (32 rows),
// 128-255: xy (16 K-rows + 16 KT-rows). Per-matrix barriers; tol-based early exit.
__global__ __launch_bounds__(1024) void coop_k(const float* __restrict__ C,
                                               float* __restrict__ Pa,
                                               float* __restrict__ Pb,
                                               float* __restrict__ ug,
                                               float* __restrict__ vg,
                                               float* __restrict__ maxsl,
                                               int* __restrict__ sync_){
    extern __shared__ char smem[];
    __half* Kl   = (__half*)smem;              // 32 rows (sym) or 16 K rows (xy)
    __half* KTl  = (__half*)(smem + 65536);    // xy: 16 KT rows
    float*  sRed = (float*)(smem + 131072);    // 16
    int*    sVote= (int*)(smem + 131072 + 64);
    int* bcnt = sync_;        // [3*2]
    int* bgen = sync_ + 8;    // [3]
    int* ccnt = sync_ + 12;   // [3*2]

    const int tid = threadIdx.x;
    const int w = tid >> 6, lane = tid & 63;
    int bid = blockIdx.x;
    int m, nblk, row0, nrows;
    if(bid < 64)      { m=0; nblk=64;  nrows=32; row0=bid*32; }
    else if(bid <128) { m=2; nblk=64;  nrows=32; row0=(bid-64)*32; }
    else              { m=1; nblk=128; nrows=16; row0=(bid-128)*16; }
    const float* Cm = C + (size_t)m*NM;
    float* um = ug + m*N;
    float* vm = vg + m*N;
    const float lp0 = __logf(P0CONST + EPSF);
    int bcount = 0;

#define MATBAR() do{ \
    __syncthreads(); \
    if(tid==0){ \
        __threadfence(); \
        if(atomicAdd(&bcnt[m*2+(bcount&1)],1)==nblk-1){ \
            atomicExch(&bcnt[m*2+(bcount&1)],0); \
            __threadfence(); \
            atomicExch(&bgen[m], bcount+1); \
        } else { \
            while(__hip_atomic_load(&bgen[m], __ATOMIC_RELAXED, __HIP_MEMORY_SCOPE_AGENT) < bcount+1) \
                __builtin_amdgcn_s_sleep(4); \
            __threadfence(); \
        } \
    } \
    bcount++; \
    __syncthreads(); \
}while(0)

    // one Sinkhorn half-step: gout[row] = INV_N / (S_row . gin), rows owned by this block
    auto halfstep = [&](const __half* S, const float* gin, float* gout, bool constU, bool vote){
        float4 ua[8];
        if(!constU){
            const float4* g4 = (const float4*)(gin + lane*32);
#pragma unroll
            for(int j=0;j<8;++j) ua[j]=g4[j];
        }
        const int rpw = (m==1)?1:2;
        for(int rr=0; rr<rpw; ++rr){
            int rl = w*rpw + rr;
            const float4* k4 = (const float4*)(S + (size_t)rl*2048);
            float s=0.f;
#pragma unroll
            for(int i=0;i<4;++i){
                float4 kb = k4[i*64+lane];
                const __half2* h=(const __half2*)&kb;
                float2 f0=__half22float2(h[0]),f1=__half22float2(h[1]),
                       f2=__half22float2(h[2]),f3=__half22float2(h[3]);
                if(constU) s += f0.x+f0.y+f1.x+f1.y+f2.x+f2.y+f3.x+f3.y;
                else s += f0.x*ua[2*i].x+f0.y*ua[2*i].y+f1.x*ua[2*i].z+f1.y*ua[2*i].w
                        + f2.x*ua[2*i+1].x+f2.y*ua[2*i+1].y+f3.x*ua[2*i+1].z+f3.y*ua[2*i+1].w;
            }
            s = waveReduceSum(s);
            if(constU) s *= INV_N;
            float nv = INV_N/s;
            if(lane==0){
                if(vote){
                    float ov = gout[row0+rl];
                    if(!(fabsf(nv-ov) <= TOL*nv)) sVote[0]=0;
                }
                gout[row0+rl] = nv;
            }
        }
    };

    for(int t=0; t<PROX; ++t){
        const float* Pin = (t&1) ? Pa : Pb;   // stage t reads P written at stage t-1
        float*       Pout= (t&1) ? Pb : Pa;
        const float* Pm  = Pin + (size_t)m*NM;
        // ---- phase A: global max of M = C - reg*log(P+eps) over own rows ----
        float mx = -1e30f;
        for(int r=0;r<nrows;++r){
            size_t base = (size_t)(row0+r)*N;
            float c0 = Cm[base+tid], c1 = Cm[base+tid+1024];
            float l0=lp0, l1=lp0;
            if(t){ l0=__logf(Pm[base+tid]+EPSF); l1=__logf(Pm[base+tid+1024]+EPSF); }
            mx = fmaxf(mx, fmaxf(c0-REG*l0, c1-REG*l1));
        }
        mx = waveReduceMax(mx);
        if(lane==0) sRed[w]=mx;
        __syncthreads();
        if(tid==0){
            float bm=sRed[0];
#pragma unroll
            for(int i=1;i<16;++i) bm=fmaxf(bm,sRed[i]);
            atomicMax((unsigned int*)&maxsl[m*PROX+t], __float_as_uint(bm)); // all M > 0
            atomicExch(&ccnt[m*2+0],0);
            atomicExch(&ccnt[m*2+1],0);
        }
        MATBAR();
        float invmx = 1.0f / maxsl[m*PROX+t];
        // ---- phase B: K' = KSCALE*exp(-10*Mhat) -> LDS (swizzled) ----
        for(int r=0;r<nrows;++r){
            size_t base=(size_t)(row0+r)*N;
#pragma unroll
            for(int h=0;h<2;++h){
                int c = tid + h*1024;
                float cc = Cm[base+c];
                float l = t ? __logf(Pm[base+c]+EPSF) : lp0;
                float Kv = __expf((cc-REG*l)*invmx*-10.0f)*KSCALE;
                Kl[r*2048 + swz(c)] = __float2half(Kv);
            }
        }
        if(m==1){
            for(int pass=0;pass<32;++pass){
                int i = pass*64 + (tid>>4); int jj = tid&15; int j = row0+jj;
                float cc = Cm[(size_t)i*N + j];
                float l = t ? __logf(Pm[(size_t)i*N+j]+EPSF) : lp0;
                float Kv = __expf((cc-REG*l)*invmx*-10.0f)*KSCALE;
                KTl[jj*2048 + swz(i)] = __float2half(Kv);
            }
        }
        __syncthreads();
        // ---- Sinkhorn loop ----
        for(int it=0; it<SINK; ++it){
            halfstep((m==1)?KTl:Kl, um, vm, it==0, false);   // v = q/(K^T u)
            MATBAR();
            if(tid==0) sVote[0]=1;
            __syncthreads();
            halfstep(Kl, vm, um, false, true);               // u = p/(K v), vote
            __syncthreads();
            if(tid==0 && sVote[0] && it>=3) atomicAdd(&ccnt[m*2+(it&1)],1);
            MATBAR();
            int cc = *(volatile int*)&ccnt[m*2+(it&1)];
            if(tid==0) atomicExch(&ccnt[m*2+((it+1)&1)],0);
            if(cc==nblk) break;                              // uniform per matrix
        }
        halfstep((m==1)?KTl:Kl, um, vm, false, false);       // final v
        MATBAR();
        // ---- P build: P = u_i * K'_ij * v'_j (scale cancels) ----
        {
            float* Pom = Pout + (size_t)m*NM;
            for(int r=0;r<nrows;++r){
                size_t base=(size_t)(row0+r)*N;
                float uu = um[row0+r];
                float k0 = __half2float(Kl[r*2048+swz(tid)]);
                float k1 = __half2float(Kl[r*2048+swz(tid+1024)]);
                Pom[base+tid]      = uu*k0*vm[tid];
                Pom[base+tid+1024] = uu*k1*vm[tid+1024];
            }
        }
        MATBAR();   // next stage's phase A reads Pout
    }
#undef MATBAR
}

// ---------------- column sums of normalized M_final (from C and P4) ----------------
__global__ __launch_bounds__(256) void colsumM_k(const float* __restrict__ Cb,
                                                 const float* __restrict__ Pb,
                                                 const float* __restrict__ maxsl, int slot,
                                                 float* __restrict__ colM){
    int mat = blockIdx.y;
    const float4* C4 = (const float4*)(Cb + (size_t)mat*NM);
    const float4* P4 = (const float4*)(Pb + (size_t)mat*NM);
    float invmx = 1.0f / maxsl[mat*PROX + slot];
    int r0 = blockIdx.x*32;
    float4 a0 = {0,0,0,0}, a1 = {0,0,0,0};
    for(int r=0;r<32;++r){
        int base = (r0 + r)*512;
        {
            float4 c = C4[base + threadIdx.x]; float4 p = P4[base + threadIdx.x];
            a0.x += (c.x - REG*logf(p.x+EPSF))*invmx;
            a0.y += (c.y - REG*logf(p.y+EPSF))*invmx;
            a0.z += (c.z - REG*logf(p.z+EPSF))*invmx;
            a0.w += (c.w - REG*logf(p.w+EPSF))*invmx;
        }
        {
            float4 c = C4[base + 256 + threadIdx.x]; float4 p = P4[base + 256 + threadIdx.x];
            a1.x += (c.x - REG*logf(p.x+EPSF))*invmx;
            a1.y += (c.y - REG*logf(p.y+EPSF))*invmx;
            a1.z += (c.z - REG*logf(p.z+EPSF))*invmx;
            a1.w += (c.w - REG*logf(p.w+EPSF))*invmx;
        }
    }
    float* cm = colM + mat*N;
    atomicAdd(cm + 4*threadIdx.x + 0, a0.x);
    atomicAdd(cm + 4*threadIdx.x + 1, a0.y);
    atomicAdd(cm + 4*threadIdx.x + 2, a0.z);
    atomicAdd(cm + 4*threadIdx.x + 3, a0.w);
    atomicAdd(cm + 1024 + 4*threadIdx.x + 0, a1.x);
    atomicAdd(cm + 1024 + 4*threadIdx.x + 1, a1.y);
    atomicAdd(cm + 1024 + 4*threadIdx.x + 2, a1.z);
    atomicAdd(cm + 1024 + 4*threadIdx.x + 3, a1.w);
}

// ---------------- column sums of T (=P5) and log(T+eps) ----------------
__global__ __launch_bounds__(256) void colsumTL_k(const float* __restrict__ Pb,
                                                  float* __restrict__ colT,
                                                  float* __restrict__ colL){
    int mat = blockIdx.y;
    const float4* P4 = (const float4*)(Pb + (size_t)mat*NM);
    int r0 = blockIdx.x*32;
    float4 t0 = {0,0,0,0}, t1 = {0,0,0,0};
    float4 l0 = {0,0,0,0}, l1 = {0,0,0,0};
    for(int r=0;r<32;++r){
        int base = (r0 + r)*512;
        {
            float4 p = P4[base + threadIdx.x];
            t0.x += p.x; t0.y += p.y; t0.z += p.z; t0.w += p.w;
            l0.x += logf(p.x+EPSF); l0.y += logf(p.y+EPSF);
            l0.z += logf(p.z+EPSF); l0.w += logf(p.w+EPSF);
        }
        {
            float4 p = P4[base + 256 + threadIdx.x];
            t1.x += p.x; t1.y += p.y; t1.z += p.z; t1.w += p.w;
            l1.x += logf(p.x+EPSF); l1.y += logf(p.y+EPSF);
            l1.z += logf(p.z+EPSF); l1.w += logf(p.w+EPSF);
        }
    }
    float* ct = colT + mat*N;
    float* cl = colL + mat*N;
    atomicAdd(ct + 4*threadIdx.x + 0, t0.x);
    atomicAdd(ct + 4*threadIdx.x + 1, t0.y);
    atomicAdd(ct + 4*threadIdx.x + 2, t0.z);
    atomicAdd(ct + 4*threadIdx.x + 3, t0.w);
    atomicAdd(ct + 1024 + 4*threadIdx.x + 0, t1.x);
    atomicAdd(ct + 1024 + 4*threadIdx.x + 1, t1.y);
    atomicAdd(ct + 1024 + 4*threadIdx.x + 2, t1.z);
    atomicAdd(ct + 1024 + 4*threadIdx.x + 3, t1.w);
    atomicAdd(cl + 4*threadIdx.x + 0, l0.x);
    atomicAdd(cl + 4*threadIdx.x + 1, l0.y);
    atomicAdd(cl + 4*threadIdx.x + 2, l0.z);
    atomicAdd(cl + 4*threadIdx.x + 3, l0.w);
    atomicAdd(cl + 1024 + 4*threadIdx.x + 0, l1.x);
    atomicAdd(cl + 1024 + 4*threadIdx.x + 1, l1.y);
    atomicAdd(cl + 1024 + 4*threadIdx.x + 2, l1.z);
    atomicAdd(cl + 1024 + 4*threadIdx.x + 3, l1.w);
}

// ---------------- final combine ----------------
__global__ __launch_bounds__(256) void final_k(const float* __restrict__ colM,
                                               const float* __restrict__ colT,
                                               const float* __restrict__ colL,
                                               float* __restrict__ out){
    __shared__ float red[8];
    __shared__ float divs[3];
    for(int mat=0; mat<3; ++mat){
        float s1=0.f, s2=0.f;
        for(int j=threadIdx.x; j<N; j+=256){
            float t = colT[mat*N+j];
            s1 += t * colM[mat*N+j];
            s2 += t * (colL[mat*N+j] - (float)N);
        }
        s1 = waveReduceSum(s1); s2 = waveReduceSum(s2);
        int w = threadIdx.x>>6, lane = threadIdx.x&63;
        if(lane==0){ red[w] = s1; red[4+w] = s2; }
        __syncthreads();
        if(threadIdx.x==0){
            float a = red[0]+red[1]+red[2]+red[3];
            float b = red[4]+red[5]+red[6]+red[7];
            divs[mat] = (a + REG*b) * (1.0f/((float)N*(float)N));
        }
        __syncthreads();
    }
    if(threadIdx.x==0) out[0] = divs[1] - 0.5f*(divs[0] + divs[2]);
}

extern "C" void kernel_launch(void* const* d_in, const int* in_sizes, int n_in,
                              void* d_out, int out_size, void* d_ws, size_t ws_size,
                              hipStream_t stream){
    const float* x = (const float*)d_in[0];
    const float* y = (const float*)d_in[1];
    float* ws = (float*)d_ws;
    // layout: C[3NM] Pa[3NM] Pb[3NM] | ug[3N] vg[3N] nx[N] ny[N] | zeroed tail
    float* C    = ws;
    float* Pa   = C  + (size_t)3*NM;
    float* Pb   = Pa + (size_t)3*NM;
    float* ug   = Pb + (size_t)3*NM;
    float* vg   = ug + 3*N;
    float* nx   = vg + 3*N;
    float* ny   = nx + N;
    float* zb   = ny + N;
    float* maxsl= zb;                  // 16 floats
    float* colM = zb + 16;             // 3N
    float* colT = colM + 3*N;          // 3N
    float* colL = colT + 3*N;          // 3N
    int*   sync_= (int*)(colL + 3*N);  // 32 ints (bcnt[6], bgen[3], ccnt[6])
    size_t zbytes = (16 + (size_t)9*N)*sizeof(float) + 32*sizeof(int);
    hipMemsetAsync(zb, 0, zbytes, stream);

    norms_k <<<dim3(512,2), 256, 0, stream>>>(x, y, nx, ny);
    sqdist_k<<<dim3(1024,3),256, 0, stream>>>(x, y, nx, ny, C);

    hipFuncSetAttribute((const void*)coop_k,
                        hipFuncAttributeMaxDynamicSharedMemorySize, SMEM_BYTES);
    void* args[] = {(void*)&C, (void*)&Pa, (void*)&Pb, (void*)&ug, (void*)&vg,
                    (void*)&maxsl, (void*)&sync_};
    hipLaunchCooperativeKernel((void*)coop_k, dim3(256), dim3(1024),
                               args, SMEM_BYTES, stream);

    // P4 (T_pre) is in Pb (written at stage 3), P5 (T) in Pa (stage 4)
    colsumM_k <<<dim3(64,3), 256, 0, stream>>>(C, Pb, maxsl, 4, colM);
    colsumTL_k<<<dim3(64,3), 256, 0, stream>>>(Pa, colT, colL);
    final_k   <<<1, 256, 0, stream>>>(colM, colT, colL, (float*)d_out);
}

// Round 6
// 1552.428 us; speedup vs baseline: 6.0852x; 2.5972x over previous
//
#include <hip/hip_runtime.h>
#include <hip/hip_fp16.h>
#include <math.h>

#define N 2048
#define D 256
#define NM (N*N)
#define REG 0.1f
#define EPSF 1e-10f
#define INV_N (1.0f/2048.0f)
#define P0CONST (1.0f/(2048.0f*2048.0f))
#define PROX 5
#define SINK 100
#define KSCALE 256.0f       // cancels exactly in Sinkhorn (u, P invariant)
#define TOL 1e-5f
#define SMEM_BYTES (131072 + 256)
#define SYS 64              // sync slot stride in ints (256B -> no false sharing)

__device__ __forceinline__ float waveReduceSum(float v){
#pragma unroll
    for(int o=32;o;o>>=1) v += __shfl_xor(v,o,64);
    return v;
}
__device__ __forceinline__ float waveReduceMax(float v){
#pragma unroll
    for(int o=32;o;o>>=1) v = fmaxf(v, __shfl_xor(v,o,64));
    return v;
}

// lane-contiguous LDS swizzle: column c (0..2047) -> half-index within row.
__device__ __forceinline__ int swz(int c){
    return ((c>>3)&3)*512 + ((c>>5)<<3) + (c&7);
}

// ---------------- row squared-norms of x and y ----------------
__global__ __launch_bounds__(256) void norms_k(const float* __restrict__ x,
                                               const float* __restrict__ y,
                                               float* __restrict__ nx,
                                               float* __restrict__ ny){
    const float* src = blockIdx.y ? y : x;
    float* dst       = blockIdx.y ? ny : nx;
    int w = threadIdx.x >> 6, lane = threadIdx.x & 63;
    int row = blockIdx.x*4 + w;
    const float4* r4 = (const float4*)(src + (size_t)row*D);
    float4 f = r4[lane];
    float s = f.x*f.x + f.y*f.y + f.z*f.z + f.w*f.w;
    s = waveReduceSum(s);
    if(lane==0) dst[row] = s;
}

// ---------------- C = |a_i|^2 + |b_j|^2 - 2 a_i.b_j  (3 matrices) --------
// accumulation order identical for (i,j)/(j,i) -> C_xx, C_yy bitwise symmetric.
__global__ __launch_bounds__(256) void sqdist_k(const float* __restrict__ x,
                                                const float* __restrict__ y,
                                                const float* __restrict__ nx,
                                                const float* __restrict__ ny,
                                                float* __restrict__ Cb){
    int mat = blockIdx.y;
    const float* A  = (mat<2)  ? x  : y;
    const float* B  = (mat==0) ? x  : y;
    const float* na = (mat<2)  ? nx : ny;
    const float* nb = (mat==0) ? nx : ny;
    float* Cm = Cb + (size_t)mat*NM;
    int bm = blockIdx.x >> 5, bn = blockIdx.x & 31;
    __shared__ float As[32][68];
    __shared__ float Bs[32][68];
    int tid = threadIdx.x;
    int tr = tid >> 4, tc = tid & 15;
    float acc[4][4] = {};
    for(int kb=0; kb<8; ++kb){
#pragma unroll
        for(int i=0;i<2;++i){
            int id = tid + 256*i;
            int r = id >> 3, c4 = id & 7;
            float4 a = *(const float4*)(A + (size_t)(bm*64 + r)*D + kb*32 + c4*4);
            As[c4*4+0][r]=a.x; As[c4*4+1][r]=a.y; As[c4*4+2][r]=a.z; As[c4*4+3][r]=a.w;
            float4 b = *(const float4*)(B + (size_t)(bn*64 + r)*D + kb*32 + c4*4);
            Bs[c4*4+0][r]=b.x; Bs[c4*4+1][r]=b.y; Bs[c4*4+2][r]=b.z; Bs[c4*4+3][r]=b.w;
        }
        __syncthreads();
#pragma unroll
        for(int d=0; d<32; ++d){
            float4 a = *(const float4*)&As[d][4*tr];
            float4 b = *(const float4*)&Bs[d][4*tc];
            acc[0][0] += a.x*b.x; acc[0][1] += a.x*b.y; acc[0][2] += a.x*b.z; acc[0][3] += a.x*b.w;
            acc[1][0] += a.y*b.x; acc[1][1] += a.y*b.y; acc[1][2] += a.y*b.z; acc[1][3] += a.y*b.w;
            acc[2][0] += a.z*b.x; acc[2][1] += a.z*b.y; acc[2][2] += a.z*b.z; acc[2][3] += a.z*b.w;
            acc[3][0] += a.w*b.x; acc[3][1] += a.w*b.y; acc[3][2] += a.w*b.z; acc[3][3] += a.w*b.w;
        }
        __syncthreads();
    }
    float nb0 = nb[bn*64 + tc*4 + 0];
    float nb1 = nb[bn*64 + tc*4 + 1];
    float nb2 = nb[bn*64 + tc*4 + 2];
    float nb3 = nb[bn*64 + tc*4 + 3];
#pragma unroll
    for(int i=0;i<4;++i){
        int row = bm*64 + tr*4 + i;
        float nr = na[row];
        float4 o;
        o.x = nr + nb0 - 2.0f*acc[i][0];
        o.y = nr + nb1 - 2.0f*acc[i][1];
        o.z = nr + nb2 - 2.0f*acc[i][2];
        o.w = nr + nb3 - 2.0f*acc[i][3];
        *(float4*)(Cm + (size_t)row*N + bn*64 + tc*4) = o;
    }
}

// ================= persistent cooperative kernel: full 3-chain prox-Sinkhorn =============
// 256 blocks x 1024 threads. Blocks 0-63: xx, 64-127: yy, 128-255: xy.
// Per-matrix padded barriers (256B/slot); tol-based early exit; warm-started u.
__global__ __launch_bounds__(1024) void coop_k(const float* __restrict__ C,
                                               float* __restrict__ Pa,
                                               float* __restrict__ Pb,
                                               float* __restrict__ ug,
                                               float* __restrict__ vg,
                                               float* __restrict__ maxsl,
                                               int* __restrict__ sync_){
    extern __shared__ char smem[];
    __half* Kl   = (__half*)smem;              // 32 rows (sym) or 16 K rows (xy)
    __half* KTl  = (__half*)(smem + 65536);    // xy: 16 KT rows
    float*  sRed = (float*)(smem + 131072);
    int*    sVote= (int*)(smem + 131072 + 64);

    const int tid = threadIdx.x;
    const int w = tid >> 6, lane = tid & 63;
    int bid = blockIdx.x;
    int m, nblk, row0, nrows;
    if(bid < 64)      { m=0; nblk=64;  nrows=32; row0=bid*32; }
    else if(bid <128) { m=2; nblk=64;  nrows=32; row0=(bid-64)*32; }
    else              { m=1; nblk=128; nrows=16; row0=(bid-128)*16; }
    // padded sync slots: 5 per matrix, 64 ints (256B) apart
    int* SY0 = sync_ + m*5*SYS;      // bcnt parity0
    int* SY1 = SY0 + SYS;            // bcnt parity1
    int* SYG = SY0 + 2*SYS;          // bgen
    int* SYC0= SY0 + 3*SYS;          // ccnt parity0
    int* SYC1= SY0 + 4*SYS;          // ccnt parity1
    const float* Cm = C + (size_t)m*NM;
    float* um = ug + m*N;
    float* vm = vg + m*N;
    const float lp0 = __logf(P0CONST + EPSF);
    int bcount = 0;

#define MATBAR() do{ \
    __syncthreads(); \
    if(tid==0){ \
        int* bc = (bcount&1) ? SY1 : SY0; \
        __threadfence(); \
        if(atomicAdd(bc,1)==nblk-1){ \
            atomicExch(bc,0); \
            __threadfence(); \
            atomicExch(SYG, bcount+1); \
        } else { \
            while(__hip_atomic_load(SYG, __ATOMIC_RELAXED, __HIP_MEMORY_SCOPE_AGENT) < bcount+1) \
                __builtin_amdgcn_s_sleep(1); \
            __threadfence(); \
        } \
    } \
    bcount++; \
    __syncthreads(); \
}while(0)

    // one Sinkhorn half-step: gout[row] = INV_N / (S_row . gin)
    auto halfstep = [&](const __half* S, const float* gin, float* gout, bool constU, bool vote){
        float4 ua[8];
        if(!constU){
            const float4* g4 = (const float4*)(gin + lane*32);
#pragma unroll
            for(int j=0;j<8;++j) ua[j]=g4[j];
        }
        const int rpw = (m==1)?1:2;
        for(int rr=0; rr<rpw; ++rr){
            int rl = w*rpw + rr;
            const float4* k4 = (const float4*)(S + (size_t)rl*2048);
            float s=0.f;
#pragma unroll
            for(int i=0;i<4;++i){
                float4 kb = k4[i*64+lane];
                const __half2* h=(const __half2*)&kb;
                float2 f0=__half22float2(h[0]),f1=__half22float2(h[1]),
                       f2=__half22float2(h[2]),f3=__half22float2(h[3]);
                if(constU) s += f0.x+f0.y+f1.x+f1.y+f2.x+f2.y+f3.x+f3.y;
                else s += f0.x*ua[2*i].x+f0.y*ua[2*i].y+f1.x*ua[2*i].z+f1.y*ua[2*i].w
                        + f2.x*ua[2*i+1].x+f2.y*ua[2*i+1].y+f3.x*ua[2*i+1].z+f3.y*ua[2*i+1].w;
            }
            s = waveReduceSum(s);
            if(constU) s *= INV_N;
            float nv = INV_N/s;
            if(lane==0){
                if(vote){
                    float ov = gout[row0+rl];
                    if(!(fabsf(nv-ov) <= TOL*nv)) sVote[0]=0;
                }
                gout[row0+rl] = nv;
            }
        }
    };

    for(int t=0; t<PROX; ++t){
        const float* Pin = (t&1) ? Pa : Pb;
        float*       Pout= (t&1) ? Pb : Pa;
        const float* Pm  = Pin + (size_t)m*NM;
        // ---- phase A: global max of M = C - reg*log(P+eps) over own rows ----
        float mx = -1e30f;
        for(int r=0;r<nrows;++r){
            size_t base = (size_t)(row0+r)*N;
            float c0 = Cm[base+tid], c1 = Cm[base+tid+1024];
            float l0=lp0, l1=lp0;
            if(t){ l0=__logf(Pm[base+tid]+EPSF); l1=__logf(Pm[base+tid+1024]+EPSF); }
            mx = fmaxf(mx, fmaxf(c0-REG*l0, c1-REG*l1));
        }
        mx = waveReduceMax(mx);
        if(lane==0) sRed[w]=mx;
        __syncthreads();
        if(tid==0){
            float bm=sRed[0];
#pragma unroll
            for(int i=1;i<16;++i) bm=fmaxf(bm,sRed[i]);
            atomicMax((unsigned int*)&maxsl[m*SYS+t], __float_as_uint(bm)); // all M > 0
            atomicExch(SYC0,0);
            atomicExch(SYC1,0);
        }
        MATBAR();
        float invmx = 1.0f / maxsl[m*SYS+t];
        // ---- phase B: K' = KSCALE*exp(-10*Mhat) -> LDS (swizzled) ----
        for(int r=0;r<nrows;++r){
            size_t base=(size_t)(row0+r)*N;
#pragma unroll
            for(int h=0;h<2;++h){
                int c = tid + h*1024;
                float cc = Cm[base+c];
                float l = t ? __logf(Pm[base+c]+EPSF) : lp0;
                float Kv = __expf((cc-REG*l)*invmx*-10.0f)*KSCALE;
                Kl[r*2048 + swz(c)] = __float2half(Kv);
            }
        }
        if(m==1){
            for(int pass=0;pass<32;++pass){
                int i = pass*64 + (tid>>4); int jj = tid&15; int j = row0+jj;
                float cc = Cm[(size_t)i*N + j];
                float l = t ? __logf(Pm[(size_t)i*N+j]+EPSF) : lp0;
                float Kv = __expf((cc-REG*l)*invmx*-10.0f)*KSCALE;
                KTl[jj*2048 + swz(i)] = __float2half(Kv);
            }
        }
        __syncthreads();
        // ---- Sinkhorn loop (warm-started u for t>0) ----
        for(int it=0; it<SINK; ++it){
            halfstep((m==1)?KTl:Kl, um, vm, (t==0 && it==0), false);  // v = q/(K^T u)
            MATBAR();
            if(tid==0) sVote[0]=1;
            __syncthreads();
            halfstep(Kl, vm, um, false, true);                        // u = p/(K v), vote
            __syncthreads();
            if(tid==0 && sVote[0] && it>=3) atomicAdd((it&1)?SYC1:SYC0,1);
            MATBAR();
            int cc = __hip_atomic_load((it&1)?SYC1:SYC0, __ATOMIC_RELAXED,
                                       __HIP_MEMORY_SCOPE_AGENT);
            if(tid==0) atomicExch((it&1)?SYC0:SYC1,0);
            if(cc==nblk) break;                                       // uniform per matrix
        }
        halfstep((m==1)?KTl:Kl, um, vm, false, false);                // final v
        MATBAR();
        // ---- P build: P = u_i * K'_ij * v'_j (scale cancels) ----
        {
            float* Pom = Pout + (size_t)m*NM;
            for(int r=0;r<nrows;++r){
                size_t base=(size_t)(row0+r)*N;
                float uu = um[row0+r];
                float k0 = __half2float(Kl[r*2048+swz(tid)]);
                float k1 = __half2float(Kl[r*2048+swz(tid+1024)]);
                Pom[base+tid]      = uu*k0*vm[tid];
                Pom[base+tid+1024] = uu*k1*vm[tid+1024];
            }
        }
        MATBAR();   // next stage's phase A reads Pout
    }
#undef MATBAR
}

// ---------------- column sums of normalized M_final (from C and P4) ----------------
__global__ __launch_bounds__(256) void colsumM_k(const float* __restrict__ Cb,
                                                 const float* __restrict__ Pb,
                                                 const float* __restrict__ maxsl, int slot,
                                                 float* __restrict__ colM){
    int mat = blockIdx.y;
    const float4* C4 = (const float4*)(Cb + (size_t)mat*NM);
    const float4* P4 = (const float4*)(Pb + (size_t)mat*NM);
    float invmx = 1.0f / maxsl[mat*SYS + slot];
    int r0 = blockIdx.x*32;
    float4 a0 = {0,0,0,0}, a1 = {0,0,0,0};
    for(int r=0;r<32;++r){
        int base = (r0 + r)*512;
        {
            float4 c = C4[base + threadIdx.x]; float4 p = P4[base + threadIdx.x];
            a0.x += (c.x - REG*logf(p.x+EPSF))*invmx;
            a0.y += (c.y - REG*logf(p.y+EPSF))*invmx;
            a0.z += (c.z - REG*logf(p.z+EPSF))*invmx;
            a0.w += (c.w - REG*logf(p.w+EPSF))*invmx;
        }
        {
            float4 c = C4[base + 256 + threadIdx.x]; float4 p = P4[base + 256 + threadIdx.x];
            a1.x += (c.x - REG*logf(p.x+EPSF))*invmx;
            a1.y += (c.y - REG*logf(p.y+EPSF))*invmx;
            a1.z += (c.z - REG*logf(p.z+EPSF))*invmx;
            a1.w += (c.w - REG*logf(p.w+EPSF))*invmx;
        }
    }
    float* cm = colM + mat*N;
    atomicAdd(cm + 4*threadIdx.x + 0, a0.x);
    atomicAdd(cm + 4*threadIdx.x + 1, a0.y);
    atomicAdd(cm + 4*threadIdx.x + 2, a0.z);
    atomicAdd(cm + 4*threadIdx.x + 3, a0.w);
    atomicAdd(cm + 1024 + 4*threadIdx.x + 0, a1.x);
    atomicAdd(cm + 1024 + 4*threadIdx.x + 1, a1.y);
    atomicAdd(cm + 1024 + 4*threadIdx.x + 2, a1.z);
    atomicAdd(cm + 1024 + 4*threadIdx.x + 3, a1.w);
}

// ---------------- column sums of T (=P5) and log(T+eps) ----------------
__global__ __launch_bounds__(256) void colsumTL_k(const float* __restrict__ Pb,
                                                  float* __restrict__ colT,
                                                  float* __restrict__ colL){
    int mat = blockIdx.y;
    const float4* P4 = (const float4*)(Pb + (size_t)mat*NM);
    int r0 = blockIdx.x*32;
    float4 t0 = {0,0,0,0}, t1 = {0,0,0,0};
    float4 l0 = {0,0,0,0}, l1 = {0,0,0,0};
    for(int r=0;r<32;++r){
        int base = (r0 + r)*512;
        {
            float4 p = P4[base + threadIdx.x];
            t0.x += p.x; t0.y += p.y; t0.z += p.z; t0.w += p.w;
            l0.x += logf(p.x+EPSF); l0.y += logf(p.y+EPSF);
            l0.z += logf(p.z+EPSF); l0.w += logf(p.w+EPSF);
        }
        {
            float4 p = P4[base + 256 + threadIdx.x];
            t1.x += p.x; t1.y += p.y; t1.z += p.z; t1.w += p.w;
            l1.x += logf(p.x+EPSF); l1.y += logf(p.y+EPSF);
            l1.z += logf(p.z+EPSF); l1.w += logf(p.w+EPSF);
        }
    }
    float* ct = colT + mat*N;
    float* cl = colL + mat*N;
    atomicAdd(ct + 4*threadIdx.x + 0, t0.x);
    atomicAdd(ct + 4*threadIdx.x + 1, t0.y);
    atomicAdd(ct + 4*threadIdx.x + 2, t0.z);
    atomicAdd(ct + 4*threadIdx.x + 3, t0.w);
    atomicAdd(ct + 1024 + 4*threadIdx.x + 0, t1.x);
    atomicAdd(ct + 1024 + 4*threadIdx.x + 1, t1.y);
    atomicAdd(ct + 1024 + 4*threadIdx.x + 2, t1.z);
    atomicAdd(ct + 1024 + 4*threadIdx.x + 3, t1.w);
    atomicAdd(cl + 4*threadIdx.x + 0, l0.x);
    atomicAdd(cl + 4*threadIdx.x + 1, l0.y);
    atomicAdd(cl + 4*threadIdx.x + 2, l0.z);
    atomicAdd(cl + 4*threadIdx.x + 3, l0.w);
    atomicAdd(cl + 1024 + 4*threadIdx.x + 0, l1.x);
    atomicAdd(cl + 1024 + 4*threadIdx.x + 1, l1.y);
    atomicAdd(cl + 1024 + 4*threadIdx.x + 2, l1.z);
    atomicAdd(cl + 1024 + 4*threadIdx.x + 3, l1.w);
}

// ---------------- final combine ----------------
__global__ __launch_bounds__(256) void final_k(const float* __restrict__ colM,
                                               const float* __restrict__ colT,
                                               const float* __restrict__ colL,
                                               float* __restrict__ out){
    __shared__ float red[8];
    __shared__ float divs[3];
    for(int mat=0; mat<3; ++mat){
        float s1=0.f, s2=0.f;
        for(int j=threadIdx.x; j<N; j+=256){
            float t = colT[mat*N+j];
            s1 += t * colM[mat*N+j];
            s2 += t * (colL[mat*N+j] - (float)N);
        }
        s1 = waveReduceSum(s1); s2 = waveReduceSum(s2);
        int w = threadIdx.x>>6, lane = threadIdx.x&63;
        if(lane==0){ red[w] = s1; red[4+w] = s2; }
        __syncthreads();
        if(threadIdx.x==0){
            float a = red[0]+red[1]+red[2]+red[3];
            float b = red[4]+red[5]+red[6]+red[7];
            divs[mat] = (a + REG*b) * (1.0f/((float)N*(float)N));
        }
        __syncthreads();
    }
    if(threadIdx.x==0) out[0] = divs[1] - 0.5f*(divs[0] + divs[2]);
}

extern "C" void kernel_launch(void* const* d_in, const int* in_sizes, int n_in,
                              void* d_out, int out_size, void* d_ws, size_t ws_size,
                              hipStream_t stream){
    const float* x = (const float*)d_in[0];
    const float* y = (const float*)d_in[1];
    float* ws = (float*)d_ws;
    // layout: C[3NM] Pa[3NM] Pb[3NM] | ug[3N] vg[3N] nx[N] ny[N] | zeroed tail
    float* C    = ws;
    float* Pa   = C  + (size_t)3*NM;
    float* Pb   = Pa + (size_t)3*NM;
    float* ug   = Pb + (size_t)3*NM;
    float* vg   = ug + 3*N;
    float* nx   = vg + 3*N;
    float* ny   = nx + N;
    float* zb   = ny + N;
    float* maxsl= zb;                   // 3*SYS floats (padded per matrix)
    float* colM = zb + 3*SYS;           // 3N
    float* colT = colM + 3*N;           // 3N
    float* colL = colT + 3*N;           // 3N
    int*   sync_= (int*)(colL + 3*N);   // 3*5*SYS ints, padded slots
    size_t zbytes = ((size_t)3*SYS + 9*N)*sizeof(float) + (size_t)3*5*SYS*sizeof(int);
    hipMemsetAsync(zb, 0, zbytes, stream);

    norms_k <<<dim3(512,2), 256, 0, stream>>>(x, y, nx, ny);
    sqdist_k<<<dim3(1024,3),256, 0, stream>>>(x, y, nx, ny, C);

    hipFuncSetAttribute((const void*)coop_k,
                        hipFuncAttributeMaxDynamicSharedMemorySize, SMEM_BYTES);
    void* args[] = {(void*)&C, (void*)&Pa, (void*)&Pb, (void*)&ug, (void*)&vg,
                    (void*)&maxsl, (void*)&sync_};
    hipLaunchCooperativeKernel((void*)coop_k, dim3(256), dim3(1024),
                               args, SMEM_BYTES, stream);

    // P4 (T_pre) is in Pb (written at stage 3), P5 (T) in Pa (stage 4)
    colsumM_k <<<dim3(64,3), 256, 0, stream>>>(C, Pb, maxsl, 4, colM);
    colsumTL_k<<<dim3(64,3), 256, 0, stream>>>(Pa, colT, colL);
    final_k   <<<1, 256, 0, stream>>>(colM, colT, colL, (float*)d_out);
}

// Round 7
// 1369.789 us; speedup vs baseline: 6.8966x; 1.1333x over previous
//
#include <hip/hip_runtime.h>
#include <hip/hip_fp16.h>
#include <math.h>

#define N 2048
#define D 256
#define NM (N*N)
#define REG 0.1f
#define EPSF 1e-10f
#define INV_N (1.0f/2048.0f)
#define P0CONST (1.0f/(2048.0f*2048.0f))
#define PROX 5
#define SINK 100
#define KSCALE 256.0f       // cancels exactly in Sinkhorn (u, P invariant)
#define TOL 4e-6f
#define SMEM_BYTES (131072 + 256)
#define SYS 64              // sync slot stride in ints (256B -> no false sharing)

__device__ __forceinline__ float waveReduceSum(float v){
#pragma unroll
    for(int o=32;o;o>>=1) v += __shfl_xor(v,o,64);
    return v;
}
__device__ __forceinline__ float waveReduceMax(float v){
#pragma unroll
    for(int o=32;o;o>>=1) v = fmaxf(v, __shfl_xor(v,o,64));
    return v;
}

// lane-contiguous LDS swizzle: column c (0..2047) -> half-index within row.
// lane l owns columns [l*32, l*32+32).
__device__ __forceinline__ int swz(int c){
    return ((c>>3)&3)*512 + ((c>>5)<<3) + (c&7);
}

// ---------------- row squared-norms of x and y ----------------
__global__ __launch_bounds__(256) void norms_k(const float* __restrict__ x,
                                               const float* __restrict__ y,
                                               float* __restrict__ nx,
                                               float* __restrict__ ny){
    const float* src = blockIdx.y ? y : x;
    float* dst       = blockIdx.y ? ny : nx;
    int w = threadIdx.x >> 6, lane = threadIdx.x & 63;
    int row = blockIdx.x*4 + w;
    const float4* r4 = (const float4*)(src + (size_t)row*D);
    float4 f = r4[lane];
    float s = f.x*f.x + f.y*f.y + f.z*f.z + f.w*f.w;
    s = waveReduceSum(s);
    if(lane==0) dst[row] = s;
}

// ---------------- C = |a_i|^2 + |b_j|^2 - 2 a_i.b_j  (3 matrices) --------
// accumulation order identical for (i,j)/(j,i) -> C_xx, C_yy bitwise symmetric.
__global__ __launch_bounds__(256) void sqdist_k(const float* __restrict__ x,
                                                const float* __restrict__ y,
                                                const float* __restrict__ nx,
                                                const float* __restrict__ ny,
                                                float* __restrict__ Cb){
    int mat = blockIdx.y;
    const float* A  = (mat<2)  ? x  : y;
    const float* B  = (mat==0) ? x  : y;
    const float* na = (mat<2)  ? nx : ny;
    const float* nb = (mat==0) ? nx : ny;
    float* Cm = Cb + (size_t)mat*NM;
    int bm = blockIdx.x >> 5, bn = blockIdx.x & 31;
    __shared__ float As[32][68];
    __shared__ float Bs[32][68];
    int tid = threadIdx.x;
    int tr = tid >> 4, tc = tid & 15;
    float acc[4][4] = {};
    for(int kb=0; kb<8; ++kb){
#pragma unroll
        for(int i=0;i<2;++i){
            int id = tid + 256*i;
            int r = id >> 3, c4 = id & 7;
            float4 a = *(const float4*)(A + (size_t)(bm*64 + r)*D + kb*32 + c4*4);
            As[c4*4+0][r]=a.x; As[c4*4+1][r]=a.y; As[c4*4+2][r]=a.z; As[c4*4+3][r]=a.w;
            float4 b = *(const float4*)(B + (size_t)(bn*64 + r)*D + kb*32 + c4*4);
            Bs[c4*4+0][r]=b.x; Bs[c4*4+1][r]=b.y; Bs[c4*4+2][r]=b.z; Bs[c4*4+3][r]=b.w;
        }
        __syncthreads();
#pragma unroll
        for(int d=0; d<32; ++d){
            float4 a = *(const float4*)&As[d][4*tr];
            float4 b = *(const float4*)&Bs[d][4*tc];
            acc[0][0] += a.x*b.x; acc[0][1] += a.x*b.y; acc[0][2] += a.x*b.z; acc[0][3] += a.x*b.w;
            acc[1][0] += a.y*b.x; acc[1][1] += a.y*b.y; acc[1][2] += a.y*b.z; acc[1][3] += a.y*b.w;
            acc[2][0] += a.z*b.x; acc[2][1] += a.z*b.y; acc[2][2] += a.z*b.z; acc[2][3] += a.z*b.w;
            acc[3][0] += a.w*b.x; acc[3][1] += a.w*b.y; acc[3][2] += a.w*b.z; acc[3][3] += a.w*b.w;
        }
        __syncthreads();
    }
    float nb0 = nb[bn*64 + tc*4 + 0];
    float nb1 = nb[bn*64 + tc*4 + 1];
    float nb2 = nb[bn*64 + tc*4 + 2];
    float nb3 = nb[bn*64 + tc*4 + 3];
#pragma unroll
    for(int i=0;i<4;++i){
        int row = bm*64 + tr*4 + i;
        float nr = na[row];
        float4 o;
        o.x = nr + nb0 - 2.0f*acc[i][0];
        o.y = nr + nb1 - 2.0f*acc[i][1];
        o.z = nr + nb2 - 2.0f*acc[i][2];
        o.w = nr + nb3 - 2.0f*acc[i][3];
        *(float4*)(Cm + (size_t)row*N + bn*64 + tc*4) = o;
    }
}

// ================= persistent cooperative kernel: full 3-chain prox-Sinkhorn =============
// 256 blocks x 1024 threads. Blocks 0-63: xx, 64-127: yy, 128-255: xy.
// Vote fused into barrier word; phases derive log P = log u + log v + log K_LDS.
__global__ __launch_bounds__(1024) void coop_k(const float* __restrict__ C,
                                               float* __restrict__ Pa,
                                               float* __restrict__ Pb,
                                               float* __restrict__ ug,
                                               float* __restrict__ vg,
                                               float* __restrict__ maxsl,
                                               int* __restrict__ sync_){
    extern __shared__ char smem[];
    __half* Kl   = (__half*)smem;              // 32 rows (sym) or 16 K rows (xy)
    __half* KTl  = (__half*)(smem + 65536);    // xy: 16 KT rows
    float*  sRed = (float*)(smem + 131072);
    int*    sVote= (int*)(smem + 131072 + 64); // [0]=block vote box, [1]=latch flag

    const int tid = threadIdx.x;
    const int w = tid >> 6, lane = tid & 63;
    int bid = blockIdx.x;
    int m, nblk, row0, nrows;
    if(bid < 64)      { m=0; nblk=64;  nrows=32; row0=bid*32; }
    else if(bid <128) { m=2; nblk=64;  nrows=32; row0=(bid-64)*32; }
    else              { m=1; nblk=128; nrows=16; row0=(bid-128)*16; }
    int* SY0 = sync_ + m*5*SYS;      // barrier counter parity0 (low16 arrivals, high votes)
    int* SY1 = SY0 + SYS;            // parity1
    int* SYG = SY0 + 2*SYS;          // release word: gen<<1 | latchflag
    const float* Cm = C + (size_t)m*NM;
    float* um = ug + m*N;
    float* vm = vg + m*N;
    const float lp0 = __logf(P0CONST + EPSF);
    int bcount = 0;

    // barrier with fused all-vote; returns latch flag (valid when wantVote on all blocks)
    auto MATBARV = [&](int wantVote)->int{
        __syncthreads();
        if(tid==0){
            unsigned mv = wantVote ? (unsigned)sVote[0] : 0u;
            unsigned* bc = (unsigned*)((bcount&1) ? SY1 : SY0);
            int flag;
            __threadfence();
            unsigned old = atomicAdd(bc, 1u | (mv<<16));
            if((old & 0xFFFFu) == (unsigned)(nblk-1)){
                flag = (int)(((old>>16) + mv) == (unsigned)nblk);
                atomicExch(bc, 0u);
                __threadfence();
                atomicExch(SYG, ((bcount+1)<<1) | flag);
            } else {
                int g;
                for(;;){
                    g = __hip_atomic_load(SYG, __ATOMIC_RELAXED, __HIP_MEMORY_SCOPE_AGENT);
                    if((g>>1) >= bcount+1) break;
                    __builtin_amdgcn_s_sleep(1);
                }
                __threadfence();
                flag = g & 1;
            }
            sVote[1] = flag;
            sVote[0] = 1;          // re-arm vote box for next use
        }
        bcount++;
        __syncthreads();
        return sVote[1];
    };

    // one Sinkhorn half-step: gout[row] = INV_N / (S_row . gin)
    auto halfstep = [&](const __half* S, const float* gin, float* gout, bool constU, bool vote){
        float4 ua[8];
        if(!constU){
            const float4* g4 = (const float4*)(gin + lane*32);
#pragma unroll
            for(int j=0;j<8;++j) ua[j]=g4[j];
        }
        const int rpw = (m==1)?1:2;
        for(int rr=0; rr<rpw; ++rr){
            int rl = w*rpw + rr;
            const float4* k4 = (const float4*)(S + (size_t)rl*2048);
            float s=0.f;
#pragma unroll
            for(int i=0;i<4;++i){
                float4 kb = k4[i*64+lane];
                const __half2* h=(const __half2*)&kb;
                float2 f0=__half22float2(h[0]),f1=__half22float2(h[1]),
                       f2=__half22float2(h[2]),f3=__half22float2(h[3]);
                if(constU) s += f0.x+f0.y+f1.x+f1.y+f2.x+f2.y+f3.x+f3.y;
                else s += f0.x*ua[2*i].x+f0.y*ua[2*i].y+f1.x*ua[2*i].z+f1.y*ua[2*i].w
                        + f2.x*ua[2*i+1].x+f2.y*ua[2*i+1].y+f3.x*ua[2*i+1].z+f3.y*ua[2*i+1].w;
            }
            s = waveReduceSum(s);
            if(constU) s *= INV_N;
            float nv = INV_N/s;
            if(lane==0){
                if(vote){
                    float ov = gout[row0+rl];
                    if(!(fabsf(nv-ov) <= TOL*nv)) sVote[0]=0;
                }
                gout[row0+rl] = nv;
            }
        }
    };

    for(int t=0; t<PROX; ++t){
        // log v_j for own columns (prev-stage converged v'); stable through phases
        float lv0=0.f, lv1=0.f, lvt=0.f;
        if(t){
            lv0 = __logf(vm[tid]);
            lv1 = __logf(vm[tid+1024]);
            if(m==1) lvt = __logf(vm[row0+(tid&15)]);
        }
        // ---- phase A: global max of M; log P derived from u, v, K_prev(LDS) ----
        float mx = -1e30f;
        for(int r=0;r<nrows;++r){
            size_t base = (size_t)(row0+r)*N;
            float c0 = Cm[base+tid], c1 = Cm[base+tid+1024];
            float m0, m1;
            if(t==0){ m0 = c0 - REG*lp0; m1 = c1 - REG*lp0; }
            else {
                float lu = __logf(um[row0+r]);
                float k0 = __half2float(Kl[r*2048+swz(tid)]);
                float k1 = __half2float(Kl[r*2048+swz(tid+1024)]);
                m0 = c0 - REG*(lu + lv0 + __logf(k0));
                m1 = c1 - REG*(lu + lv1 + __logf(k1));
            }
            mx = fmaxf(mx, fmaxf(m0, m1));
        }
        mx = waveReduceMax(mx);
        if(lane==0) sRed[w]=mx;
        __syncthreads();
        if(tid==0){
            float bm=sRed[0];
#pragma unroll
            for(int i=1;i<16;++i) bm=fmaxf(bm,sRed[i]);
            atomicMax((unsigned int*)&maxsl[m*SYS+t], __float_as_uint(bm)); // all M > 0
        }
        MATBARV(0);
        float invmx = 1.0f / maxsl[m*SYS+t];
        // ---- phase B: K_new = KSCALE*exp(-10*Mhat), in-place elementwise over K_prev ----
        for(int r=0;r<nrows;++r){
            size_t base=(size_t)(row0+r)*N;
            float lu = t ? __logf(um[row0+r]) : 0.f;
            {
                float c0 = Cm[base+tid];
                float m0 = (t==0) ? (c0 - REG*lp0)
                    : (c0 - REG*(lu + lv0 + __logf(__half2float(Kl[r*2048+swz(tid)]))));
                Kl[r*2048+swz(tid)] = __float2half(__expf(m0*invmx*-10.0f)*KSCALE);
                float c1 = Cm[base+tid+1024];
                float m1 = (t==0) ? (c1 - REG*lp0)
                    : (c1 - REG*(lu + lv1 + __logf(__half2float(Kl[r*2048+swz(tid+1024)]))));
                Kl[r*2048+swz(tid+1024)] = __float2half(__expf(m1*invmx*-10.0f)*KSCALE);
            }
        }
        if(m==1){
            for(int pass=0;pass<32;++pass){
                int i = pass*64 + (tid>>4); int jj = tid&15;
                float cc = Cm[(size_t)i*N + row0 + jj];
                float Mv;
                if(t==0) Mv = cc - REG*lp0;
                else {
                    float lu = __logf(um[i]);
                    float kp = __half2float(KTl[jj*2048+swz(i)]);
                    Mv = cc - REG*(lu + lvt + __logf(kp));
                }
                KTl[jj*2048+swz(i)] = __float2half(__expf(Mv*invmx*-10.0f)*KSCALE);
            }
        }
        __syncthreads();
        // ---- Sinkhorn loop (warm-started u; fused-vote latch) ----
        for(int it=0; it<SINK; ++it){
            halfstep((m==1)?KTl:Kl, um, vm, (t==0 && it==0), false);  // v = q/(K^T u)
            MATBARV(0);
            halfstep(Kl, vm, um, false, true);                        // u = p/(K v), vote
            int flag = MATBARV(it>=3);
            if(flag) break;                                           // uniform per matrix
        }
        halfstep((m==1)?KTl:Kl, um, vm, false, false);                // final v
        MATBARV(0);
        // ---- P build only where needed (t=3 -> Pb = T_pre, t=4 -> Pa = T) ----
        if(t>=3){
            float* Pom = ((t&1) ? Pb : Pa) + (size_t)m*NM;
            for(int r=0;r<nrows;++r){
                size_t base=(size_t)(row0+r)*N;
                float uu = um[row0+r];
                float k0 = __half2float(Kl[r*2048+swz(tid)]);
                float k1 = __half2float(Kl[r*2048+swz(tid+1024)]);
                Pom[base+tid]      = uu*k0*vm[tid];
                Pom[base+tid+1024] = uu*k1*vm[tid+1024];
            }
        }
        // next phase A's barrier protects um/vm reads (pbuild included)
    }
}

// ---------------- column sums of normalized M_final (from C and P4) ----------------
__global__ __launch_bounds__(256) void colsumM_k(const float* __restrict__ Cb,
                                                 const float* __restrict__ Pb,
                                                 const float* __restrict__ maxsl, int slot,
                                                 float* __restrict__ colM){
    int mat = blockIdx.y;
    const float4* C4 = (const float4*)(Cb + (size_t)mat*NM);
    const float4* P4 = (const float4*)(Pb + (size_t)mat*NM);
    float invmx = 1.0f / maxsl[mat*SYS + slot];
    int r0 = blockIdx.x*32;
    float4 a0 = {0,0,0,0}, a1 = {0,0,0,0};
    for(int r=0;r<32;++r){
        int base = (r0 + r)*512;
        {
            float4 c = C4[base + threadIdx.x]; float4 p = P4[base + threadIdx.x];
            a0.x += (c.x - REG*logf(p.x+EPSF))*invmx;
            a0.y += (c.y - REG*logf(p.y+EPSF))*invmx;
            a0.z += (c.z - REG*logf(p.z+EPSF))*invmx;
            a0.w += (c.w - REG*logf(p.w+EPSF))*invmx;
        }
        {
            float4 c = C4[base + 256 + threadIdx.x]; float4 p = P4[base + 256 + threadIdx.x];
            a1.x += (c.x - REG*logf(p.x+EPSF))*invmx;
            a1.y += (c.y - REG*logf(p.y+EPSF))*invmx;
            a1.z += (c.z - REG*logf(p.z+EPSF))*invmx;
            a1.w += (c.w - REG*logf(p.w+EPSF))*invmx;
        }
    }
    float* cm = colM + mat*N;
    atomicAdd(cm + 4*threadIdx.x + 0, a0.x);
    atomicAdd(cm + 4*threadIdx.x + 1, a0.y);
    atomicAdd(cm + 4*threadIdx.x + 2, a0.z);
    atomicAdd(cm + 4*threadIdx.x + 3, a0.w);
    atomicAdd(cm + 1024 + 4*threadIdx.x + 0, a1.x);
    atomicAdd(cm + 1024 + 4*threadIdx.x + 1, a1.y);
    atomicAdd(cm + 1024 + 4*threadIdx.x + 2, a1.z);
    atomicAdd(cm + 1024 + 4*threadIdx.x + 3, a1.w);
}

// ---------------- column sums of T (=P5) and log(T+eps) ----------------
__global__ __launch_bounds__(256) void colsumTL_k(const float* __restrict__ Pb,
                                                  float* __restrict__ colT,
                                                  float* __restrict__ colL){
    int mat = blockIdx.y;
    const float4* P4 = (const float4*)(Pb + (size_t)mat*NM);
    int r0 = blockIdx.x*32;
    float4 t0 = {0,0,0,0}, t1 = {0,0,0,0};
    float4 l0 = {0,0,0,0}, l1 = {0,0,0,0};
    for(int r=0;r<32;++r){
        int base = (r0 + r)*512;
        {
            float4 p = P4[base + threadIdx.x];
            t0.x += p.x; t0.y += p.y; t0.z += p.z; t0.w += p.w;
            l0.x += logf(p.x+EPSF); l0.y += logf(p.y+EPSF);
            l0.z += logf(p.z+EPSF); l0.w += logf(p.w+EPSF);
        }
        {
            float4 p = P4[base + 256 + threadIdx.x];
            t1.x += p.x; t1.y += p.y; t1.z += p.z; t1.w += p.w;
            l1.x += logf(p.x+EPSF); l1.y += logf(p.y+EPSF);
            l1.z += logf(p.z+EPSF); l1.w += logf(p.w+EPSF);
        }
    }
    float* ct = colT + mat*N;
    float* cl = colL + mat*N;
    atomicAdd(ct + 4*threadIdx.x + 0, t0.x);
    atomicAdd(ct + 4*threadIdx.x + 1, t0.y);
    atomicAdd(ct + 4*threadIdx.x + 2, t0.z);
    atomicAdd(ct + 4*threadIdx.x + 3, t0.w);
    atomicAdd(ct + 1024 + 4*threadIdx.x + 0, t1.x);
    atomicAdd(ct + 1024 + 4*threadIdx.x + 1, t1.y);
    atomicAdd(ct + 1024 + 4*threadIdx.x + 2, t1.z);
    atomicAdd(ct + 1024 + 4*threadIdx.x + 3, t1.w);
    atomicAdd(cl + 4*threadIdx.x + 0, l0.x);
    atomicAdd(cl + 4*threadIdx.x + 1, l0.y);
    atomicAdd(cl + 4*threadIdx.x + 2, l0.z);
    atomicAdd(cl + 4*threadIdx.x + 3, l0.w);
    atomicAdd(cl + 1024 + 4*threadIdx.x + 0, l1.x);
    atomicAdd(cl + 1024 + 4*threadIdx.x + 1, l1.y);
    atomicAdd(cl + 1024 + 4*threadIdx.x + 2, l1.z);
    atomicAdd(cl + 1024 + 4*threadIdx.x + 3, l1.w);
}

// ---------------- final combine ----------------
__global__ __launch_bounds__(256) void final_k(const float* __restrict__ colM,
                                               const float* __restrict__ colT,
                                               const float* __restrict__ colL,
                                               float* __restrict__ out){
    __shared__ float red[8];
    __shared__ float divs[3];
    for(int mat=0; mat<3; ++mat){
        float s1=0.f, s2=0.f;
        for(int j=threadIdx.x; j<N; j+=256){
            float t = colT[mat*N+j];
            s1 += t * colM[mat*N+j];
            s2 += t * (colL[mat*N+j] - (float)N);
        }
        s1 = waveReduceSum(s1); s2 = waveReduceSum(s2);
        int w = threadIdx.x>>6, lane = threadIdx.x&63;
        if(lane==0){ red[w] = s1; red[4+w] = s2; }
        __syncthreads();
        if(threadIdx.x==0){
            float a = red[0]+red[1]+red[2]+red[3];
            float b = red[4]+red[5]+red[6]+red[7];
            divs[mat] = (a + REG*b) * (1.0f/((float)N*(float)N));
        }
        __syncthreads();
    }
    if(threadIdx.x==0) out[0] = divs[1] - 0.5f*(divs[0] + divs[2]);
}

extern "C" void kernel_launch(void* const* d_in, const int* in_sizes, int n_in,
                              void* d_out, int out_size, void* d_ws, size_t ws_size,
                              hipStream_t stream){
    const float* x = (const float*)d_in[0];
    const float* y = (const float*)d_in[1];
    float* ws = (float*)d_ws;
    // layout: C[3NM] Pa[3NM] Pb[3NM] | ug[3N] vg[3N] nx[N] ny[N] | zeroed tail
    float* C    = ws;
    float* Pa   = C  + (size_t)3*NM;
    float* Pb   = Pa + (size_t)3*NM;
    float* ug   = Pb + (size_t)3*NM;
    float* vg   = ug + 3*N;
    float* nx   = vg + 3*N;
    float* ny   = nx + N;
    float* zb   = ny + N;
    float* maxsl= zb;                   // 3*SYS floats (padded per matrix)
    float* colM = zb + 3*SYS;           // 3N
    float* colT = colM + 3*N;           // 3N
    float* colL = colT + 3*N;           // 3N
    int*   sync_= (int*)(colL + 3*N);   // 3*5*SYS ints, padded slots
    size_t zbytes = ((size_t)3*SYS + 9*N)*sizeof(float) + (size_t)3*5*SYS*sizeof(int);
    hipMemsetAsync(zb, 0, zbytes, stream);

    norms_k <<<dim3(512,2), 256, 0, stream>>>(x, y, nx, ny);
    sqdist_k<<<dim3(1024,3),256, 0, stream>>>(x, y, nx, ny, C);

    hipFuncSetAttribute((const void*)coop_k,
                        hipFuncAttributeMaxDynamicSharedMemorySize, SMEM_BYTES);
    void* args[] = {(void*)&C, (void*)&Pa, (void*)&Pb, (void*)&ug, (void*)&vg,
                    (void*)&maxsl, (void*)&sync_};
    hipLaunchCooperativeKernel((void*)coop_k, dim3(256), dim3(1024),
                               args, SMEM_BYTES, stream);

    // P4 (T_pre) in Pb (stage 3), P5 (T) in Pa (stage 4)
    colsumM_k <<<dim3(64,3), 256, 0, stream>>>(C, Pb, maxsl, 4, colM);
    colsumTL_k<<<dim3(64,3), 256, 0, stream>>>(Pa, colT, colL);
    final_k   <<<1, 256, 0, stream>>>(colM, colT, colL, (float*)d_out);
}